// Round 15
// baseline (82462.573 us; speedup 1.0000x reference)
//
#include <hip/hip_runtime.h>
#include <math.h>

#define NT  256
#define NWG 64
#define SCOPE_AG __HIP_MEMORY_SCOPE_AGENT
typedef unsigned long long ull;

// ---------- agent-scope (coherence-point) atomic helpers ----------
__device__ __forceinline__ float ld_f(const float* p) {
    return __hip_atomic_load(p, __ATOMIC_RELAXED, SCOPE_AG);
}
__device__ __forceinline__ void st_f(float* p, float v) {
    __hip_atomic_store(p, v, __ATOMIC_RELAXED, SCOPE_AG);
}
__device__ __forceinline__ unsigned ld_u(const unsigned* p) {
    return __hip_atomic_load(p, __ATOMIC_RELAXED, SCOPE_AG);
}
__device__ __forceinline__ void st_u_rel(unsigned* p, unsigned v) {
    __hip_atomic_store(p, v, __ATOMIC_RELEASE, SCOPE_AG);
}
__device__ __forceinline__ ull ld_u64(const ull* p) {
    return __hip_atomic_load(p, __ATOMIC_RELAXED, SCOPE_AG);
}
__device__ __forceinline__ void st_u64(ull* p, ull v) {
    __hip_atomic_store(p, v, __ATOMIC_RELAXED, SCOPE_AG);
}

// mantissa tag: low 8 bits of the float carry the epoch tag (noise ~2^-17 rel)
__device__ __forceinline__ unsigned tagf(float v, unsigned tg) {
    return (__float_as_uint(v) & 0xFFFFFF00u) | tg;
}
__device__ __forceinline__ ull pack2(float lo, float hi, unsigned tg) {
    return ((ull)tagf(hi, tg) << 32) | (ull)tagf(lo, tg);
}
// bf16 pack/unpack (round-to-nearest-even); even -> low16
__device__ __forceinline__ unsigned bf16pack(float even, float odd) {
    unsigned ua = __float_as_uint(even); ua += 0x7FFFu + ((ua >> 16) & 1u);
    unsigned ub = __float_as_uint(odd);  ub += 0x7FFFu + ((ub >> 16) & 1u);
    return (ua >> 16) | (ub & 0xFFFF0000u);
}
__device__ __forceinline__ float bf16lo(unsigned w) { return __uint_as_float(w << 16); }
__device__ __forceinline__ float bf16hi(unsigned w) { return __uint_as_float(w & 0xFFFF0000u); }

__device__ __forceinline__ float wsum64(float v) {
    #pragma unroll
    for (int m = 1; m < 64; m <<= 1) v += __shfl_xor(v, m);
    return v;
}
__device__ __forceinline__ float wmax64(float v) {
    #pragma unroll
    for (int m = 1; m < 64; m <<= 1) v = fmaxf(v, __shfl_xor(v, m));
    return v;
}

// ================= ws layout (floats) =================
//   Ttab:   u32[256 pair][64 w][64 w']      @ 0         (1,048,576 floats; bf16x2)
//   partuw: ull[2 par][2 set][512][8 c]     @ 1,048,576 (32,768 floats)
//   tauws:  float[512 blk][8 b][64 w]       @ 1,081,344 (262,144 floats)
//   pm_u:   unsigned[64]                    @ 1,343,488
// total 5,374,208 B (fit proven by R13 run)
#define PART_OFF 1048576
#define TAU_OFF  1081344
#define PM_OFF   1343488

// ---------------- Gram precompute: T[pair][w][w'] = sum_d conj(A[w',d])*B[w,d] ----------------
__launch_bounds__(256, 1)
__global__ void gram_kernel(const float* __restrict__ H_re, const float* __restrict__ H_im,
                            unsigned* __restrict__ Ttab) {
    __shared__ float2 Als[64 * 65];
    __shared__ float2 Bls[64 * 65];
    const int i = blockIdx.x;            // pair index: blocks 2i, 2i+1
    const int t = threadIdx.x;
    const int w = t & 63;
    const int wp0 = (t >> 6) * 16;
    const size_t baseA = (size_t)(2 * i) * 65536;   // 64*1024
    const size_t baseB = baseA + 65536;
    float2 acc[16];
    #pragma unroll
    for (int s = 0; s < 16; ++s) acc[s] = make_float2(0.0f, 0.0f);

    for (int ch = 0; ch < 16; ++ch) {    // d-chunks of 64
        __syncthreads();
        for (int k = t; k < 4096; k += 256) {
            int r = k >> 6, d = k & 63;
            size_t off = (size_t)r * 1024 + ch * 64 + d;
            Als[r * 65 + d] = make_float2(H_re[baseA + off], H_im[baseA + off]);
            Bls[r * 65 + d] = make_float2(H_re[baseB + off], H_im[baseB + off]);
        }
        __syncthreads();
        #pragma unroll
        for (int s = 0; s < 16; ++s) {
            int wp = wp0 + s;
            float ar = 0.0f, ai = 0.0f;
            #pragma unroll 8
            for (int d = 0; d < 64; ++d) {
                float2 a = Als[wp * 65 + d];    // conj(A[w',d])
                float2 bb = Bls[w * 65 + d];
                ar += a.x * bb.x + a.y * bb.y;
                ai += a.x * bb.y - a.y * bb.x;
            }
            acc[s].x += ar; acc[s].y += ai;
        }
    }
    #pragma unroll
    for (int s = 0; s < 16; ++s)
        Ttab[(size_t)i * 4096 + w * 64 + (wp0 + s)] = bf16pack(acc[s].x, acc[s].y);
}

// ---------------- main kernel: 2 blocks per exchange, 3-bank H rotation ----------------
__launch_bounds__(NT, 1)
__global__ void robii_gram(
    const float* __restrict__ y_re, const float* __restrict__ y_im,
    const float* __restrict__ H_re, const float* __restrict__ H_im,
    const float* __restrict__ estep_w, const float* __restrict__ estep_b,
    const float* __restrict__ update_w, const float* __restrict__ update_b,
    const float* __restrict__ memory_w, const float* __restrict__ memory_b,
    float* __restrict__ out, float* __restrict__ ws)
{
    __shared__ float wTe[4096], wTu[4096], wTm[4096];
    __shared__ float be[64], bu[64], bm[64];
    __shared__ float a2s[512], xts[512], htl[512];
    __shared__ float redl[8], sgls[8], gmax[1];
    __shared__ float tauls[1024];          // [2 slot][512 (b,w)] prev-iter tau, current window
    __shared__ float2 resA[512], resB[512];
    __shared__ unsigned Tls[4160];         // [64][65] bf16x2 Gram tile (padded)
    __shared__ float2 cpartC[4][32][4];
    __shared__ float2 x_l[128];

    const int g = blockIdx.x, t = threadIdx.x;
    const int c = g & 7;
    const int b = g >> 3;
    const int lane = t & 63, wv = t >> 6;
    const int sub = t & 31;
    const int rbase = t >> 5;

    unsigned* Ttab  = (unsigned*)ws;
    ull*      partuw = (ull*)(ws + PART_OFF);
    float*    tauws  = ws + TAU_OFF;
    unsigned* pm_u   = (unsigned*)(ws + PM_OFF);

    // ---------------- init ----------------
    for (int i = t; i < 4096; i += NT) {
        int j = i >> 6, k = i & 63;
        wTe[k * 64 + j] = estep_w[i];
        wTu[k * 64 + j] = update_w[i];
        wTm[k * 64 + j] = memory_w[i];
    }
    if (t < 64) { be[t] = estep_b[t]; bu[t] = update_b[t]; bm[t] = memory_b[t]; }
    if (t < 128) x_l[t] = make_float2(0.0f, 0.0f);
    for (int i = t; i < 1024; i += NT) tauls[i] = 1.0f;
    for (int i = t; i < 4096; i += NT) st_f(&tauws[g * 4096 + i], 1.0f);

    // init sync (tag 255): publishes tau init
    __syncthreads();
    if (t == 0) st_u_rel(&pm_u[g], tagf(1.0f, 255u));
    if (t < 64) {
        while ((ld_u(&pm_u[t]) & 0xFFu) != 255u) __builtin_amdgcn_s_sleep(1);
    }
    __builtin_amdgcn_fence(__ATOMIC_ACQUIRE, "agent");
    __syncthreads();

    const size_t hcol = (size_t)c * 128 + (size_t)sub * 4;
    // 3 rotating H banks (64 VGPR each)
    float4 h0re[8], h0im[8], h1re[8], h1im[8], h2re[8], h2im[8];

#define PREF(DRE, DIM_, BLKN) do {                                                   \
        const float* _pr = H_re + ((size_t)(BLKN) * 64 + rbase) * 1024 + hcol;       \
        const float* _pi = H_im + ((size_t)(BLKN) * 64 + rbase) * 1024 + hcol;       \
        _Pragma("unroll")                                                            \
        for (int _j = 0; _j < 8; ++_j) {                                             \
            DRE[_j]  = *(const float4*)(_pr + (size_t)_j * 8192);                    \
            DIM_[_j] = *(const float4*)(_pi + (size_t)_j * 8192);                    \
        }                                                                            \
    } while (0)

    PREF(h0re, h0im, 0);   // P of window 0
    PREF(h1re, h1im, 1);   // Q of window 0

#define TCHK(V) (((((unsigned)(V)) & 0xFFu) ^ tg) | ((((unsigned)((V) >> 32)) & 0xFFu) ^ tg))

#define POLL8(PB, ZR, ZI) do {                                                       \
        ull v0,v1,v2,v3,v4,v5,v6,v7;                                                 \
        bool ok = false;                                                             \
        while (!ok) {                                                                \
            v0=ld_u64((PB)+0); v1=ld_u64((PB)+1); v2=ld_u64((PB)+2); v3=ld_u64((PB)+3); \
            v4=ld_u64((PB)+4); v5=ld_u64((PB)+5); v6=ld_u64((PB)+6); v7=ld_u64((PB)+7); \
            unsigned mm = TCHK(v0)|TCHK(v1)|TCHK(v2)|TCHK(v3)                        \
                        | TCHK(v4)|TCHK(v5)|TCHK(v6)|TCHK(v7);                       \
            ok = (mm == 0u);                                                         \
            if (!ok) __builtin_amdgcn_s_sleep(1);                                    \
        }                                                                            \
        ZR = __uint_as_float((unsigned)v0) + __uint_as_float((unsigned)v1)           \
           + __uint_as_float((unsigned)v2) + __uint_as_float((unsigned)v3)           \
           + __uint_as_float((unsigned)v4) + __uint_as_float((unsigned)v5)           \
           + __uint_as_float((unsigned)v6) + __uint_as_float((unsigned)v7);          \
        ZI = __uint_as_float((unsigned)(v0>>32)) + __uint_as_float((unsigned)(v1>>32)) \
           + __uint_as_float((unsigned)(v2>>32)) + __uint_as_float((unsigned)(v3>>32)) \
           + __uint_as_float((unsigned)(v4>>32)) + __uint_as_float((unsigned)(v5>>32)) \
           + __uint_as_float((unsigned)(v6>>32)) + __uint_as_float((unsigned)(v7>>32)); \
    } while (0)

// One Gram window: blocks K0=2gw, K1=2gw+1. P bank holds H[K0], Q holds H[K1],
// F is prefetched (during exchange) with H[2gw+2]; after Phase C, P is refilled
// with H[2gw+3]. Rotation (P,Q,F) -> (F,P,Q) each window.
#define WSTEP(GW, PRE_, PIM_, QRE_, QIM_, FRE_, FIM_) do {                           \
        const int gw_ = (GW);                                                        \
        const int par = gw_ & 1;                                                     \
        const int K0 = (2 * gw_) & 511;                                              \
        const unsigned tg = (unsigned)gw_ & 0xFFu;                                   \
        __syncthreads();                                                             \
        float2 xr0 = x_l[sub * 4 + 0], xr1 = x_l[sub * 4 + 1];                       \
        float2 xr2 = x_l[sub * 4 + 2], xr3 = x_l[sub * 4 + 3];                       \
        /* ---- Phase A-P: z_K0 partials (bank P, ready since last window) ---- */   \
        _Pragma("unroll")                                                            \
        for (int j = 0; j < 8; ++j) {                                                \
            float4 pr = PRE_[j], pi = PIM_[j];                                       \
            float sr, si;                                                            \
            sr  = xr0.x*pr.x - xr0.y*pi.x;  si  = xr0.x*pi.x + xr0.y*pr.x;           \
            sr += xr1.x*pr.y - xr1.y*pi.y;  si += xr1.x*pi.y + xr1.y*pr.y;           \
            sr += xr2.x*pr.z - xr2.y*pi.z;  si += xr2.x*pi.z + xr2.y*pr.z;           \
            sr += xr3.x*pr.w - xr3.y*pi.w;  si += xr3.x*pi.w + xr3.y*pr.w;           \
            _Pragma("unroll")                                                        \
            for (int m = 1; m < 32; m <<= 1) {                                       \
                sr += __shfl_xor(sr, m); si += __shfl_xor(si, m);                    \
            }                                                                        \
            if (sub == 0)                                                            \
                st_u64(&partuw[((size_t)(par * 2 + 0) * 512 + b * 64 + rbase + 8 * j) * 8 + c], \
                       pack2(sr, si, tg));                                           \
        }                                                                            \
        /* ---- Phase A-Q: zpre_K1 partials (bank Q, issued last window post-C) */   \
        _Pragma("unroll")                                                            \
        for (int j = 0; j < 8; ++j) {                                                \
            float4 qr = QRE_[j], qi = QIM_[j];                                       \
            float ur, ui;                                                            \
            ur  = xr0.x*qr.x - xr0.y*qi.x;  ui  = xr0.x*qi.x + xr0.y*qr.x;           \
            ur += xr1.x*qr.y - xr1.y*qi.y;  ui += xr1.x*qi.y + xr1.y*qr.y;           \
            ur += xr2.x*qr.z - xr2.y*qi.z;  ui += xr2.x*qi.z + xr2.y*qr.z;           \
            ur += xr3.x*qr.w - xr3.y*qi.w;  ui += xr3.x*qi.w + xr3.y*qr.w;           \
            _Pragma("unroll")                                                        \
            for (int m = 1; m < 32; m <<= 1) {                                       \
                ur += __shfl_xor(ur, m); ui += __shfl_xor(ui, m);                    \
            }                                                                        \
            if (sub == 0)                                                            \
                st_u64(&partuw[((size_t)(par * 2 + 1) * 512 + b * 64 + rbase + 8 * j) * 8 + c], \
                       pack2(ur, ui, tg));                                           \
        }                                                                            \
        /* ---- overlap: prefetch F bank, Gram tile, tau(next window), y ---- */     \
        int nb0 = (2 * gw_ + 2) & 511, nb1 = (2 * gw_ + 3) & 511;                    \
        PREF(FRE_, FIM_, nb0);                                                       \
        for (int q = t; q < 4096; q += NT)                                           \
            Tls[(q >> 6) * 65 + (q & 63)] = Ttab[(size_t)(gw_ & 255) * 4096 + q];    \
        float tnA0 = ld_f(&tauws[nb0 * 512 + t]);                                    \
        float tnA1 = ld_f(&tauws[nb0 * 512 + t + 256]);                              \
        float tnB0 = ld_f(&tauws[nb1 * 512 + t]);                                    \
        float tnB1 = ld_f(&tauws[nb1 * 512 + t + 256]);                              \
        float y0r[2], y0i[2], y1r[2], y1i[2];                                        \
        _Pragma("unroll")                                                            \
        for (int e = 0; e < 2; ++e) {                                                \
            int idx = t + e * 256; int bb = idx >> 6, w = idx & 63;                  \
            int n0 = K0 * 64 + w, n1 = n0 + 64;                                      \
            if (n0 < 16384) { y0r[e] = y_re[bb*16384+n0];       y0i[e] = y_im[bb*16384+n0]; } \
            else            { y0r[e] = y_re[bb*16384+n0-16384]; y0i[e] = -y_im[bb*16384+n0-16384]; } \
            if (n1 < 16384) { y1r[e] = y_re[bb*16384+n1];       y1i[e] = y_im[bb*16384+n1]; } \
            else            { y1r[e] = y_re[bb*16384+n1-16384]; y1i[e] = -y_im[bb*16384+n1-16384]; } \
        }                                                                            \
        /* ---- poll both sets (sequential 8-word rounds; low VGPR) ---- */          \
        float zpr[2], zpi[2], rr_[2], ri_[2];                                        \
        _Pragma("unroll")                                                            \
        for (int e = 0; e < 2; ++e) {                                                \
            int idx = t + e * 256;                                                   \
            float zr, zi;                                                            \
            POLL8(partuw + ((size_t)(par * 2 + 0) * 512 + idx) * 8, zr, zi);         \
            POLL8(partuw + ((size_t)(par * 2 + 1) * 512 + idx) * 8, zpr[e], zpi[e]); \
            rr_[e] = y0r[e] - zr; ri_[e] = y0i[e] - zi;                              \
            a2s[idx] = rr_[e] * rr_[e] + ri_[e] * ri_[e];                            \
        }                                                                            \
        /* ======== sub-step K0: stats + MLP (all b) + resid ======== */             \
        __syncthreads();                                                             \
        { float s_ = wsum64(a2s[t] + a2s[t + 256]);                                  \
          if (lane == 0) redl[wv] = s_; }                                            \
        __syncthreads();                                                             \
        { float mean = (redl[0]+redl[1]+redl[2]+redl[3]) * (1.0f/512.0f);            \
          float d0 = a2s[t]-mean, d1 = a2s[t+256]-mean;                              \
          float s2_ = wsum64(d0*d0 + d1*d1);                                         \
          float sgA = wsum64(a2s[wv*64 + lane]);                                     \
          float sgB = wsum64(a2s[(wv+4)*64 + lane]);                                 \
          if (lane == 0) { redl[4+wv] = s2_;                                         \
              sgls[wv] = sgA*(1.0f/64.0f); sgls[wv+4] = sgB*(1.0f/64.0f); } }        \
        __syncthreads();                                                             \
        { float stdv = sqrtf((redl[4]+redl[5]+redl[6]+redl[7]) * (1.0f/511.0f));     \
          xts[t] = a2s[t]/stdv; xts[t+256] = a2s[t+256]/stdv; }                      \
        __syncthreads();                                                             \
        _Pragma("unroll")                                                            \
        for (int e = 0; e < 2; ++e) {                                                \
            int idx = t + e*256; int bb = idx >> 6, j = idx & 63;                    \
            float acc = be[j];                                                       \
            _Pragma("unroll")                                                        \
            for (int k = 0; k < 64; ++k) acc += wTe[k*64+j] * xts[bb*64+k];          \
            htl[idx] = 1.0f/(1.0f+expf(-acc));                                       \
        }                                                                            \
        __syncthreads();                                                             \
        _Pragma("unroll")                                                            \
        for (int e = 0; e < 2; ++e) {                                                \
            int idx = t + e*256; int bb = idx >> 6, j = idx & 63;                    \
            float acc = bu[j] + bm[j];                                               \
            _Pragma("unroll")                                                        \
            for (int k = 0; k < 64; ++k)                                             \
                acc += wTu[k*64+j]*htl[bb*64+k] + wTm[k*64+j]*tauls[bb*64+k];        \
            float tn = fmaxf(acc, 0.0f);                                             \
            if (c == 0 && bb == b) st_f(&tauws[(size_t)K0 * 512 + idx], tn);         \
            float scl = tn / sgls[bb];                                               \
            resA[idx] = make_float2(rr_[e]*scl, ri_[e]*scl);                         \
        }                                                                            \
        __syncthreads();                                                             \
        /* ======== Gram correction -> z_{K0+1}, then sub-step K0+1 ======== */      \
        _Pragma("unroll")                                                            \
        for (int e = 0; e < 2; ++e) {                                                \
            int idx = t + e*256; int bb = idx >> 6, w = idx & 63;                    \
            float cr = 0.0f, ci = 0.0f;                                              \
            _Pragma("unroll 8")                                                      \
            for (int wp = 0; wp < 64; ++wp) {                                        \
                float2 rs = resA[bb*64 + wp];                                        \
                unsigned gw2 = Tls[w*65 + wp];                                       \
                float gr = bf16lo(gw2), gi = bf16hi(gw2);                            \
                cr += rs.x*gr - rs.y*gi;                                             \
                ci += rs.x*gi + rs.y*gr;                                             \
            }                                                                        \
            float z1r = zpr[e] + cr * (1.0f/65536.0f);                               \
            float z1i = zpi[e] + ci * (1.0f/65536.0f);                               \
            rr_[e] = y1r[e] - z1r; ri_[e] = y1i[e] - z1i;                            \
            a2s[idx] = rr_[e]*rr_[e] + ri_[e]*ri_[e];                                \
        }                                                                            \
        __syncthreads();                                                             \
        { float s_ = wsum64(a2s[t] + a2s[t + 256]);                                  \
          if (lane == 0) redl[wv] = s_; }                                            \
        __syncthreads();                                                             \
        { float mean = (redl[0]+redl[1]+redl[2]+redl[3]) * (1.0f/512.0f);            \
          float d0 = a2s[t]-mean, d1 = a2s[t+256]-mean;                              \
          float s2_ = wsum64(d0*d0 + d1*d1);                                         \
          float sgA = wsum64(a2s[wv*64 + lane]);                                     \
          float sgB = wsum64(a2s[(wv+4)*64 + lane]);                                 \
          if (lane == 0) { redl[4+wv] = s2_;                                         \
              sgls[wv] = sgA*(1.0f/64.0f); sgls[wv+4] = sgB*(1.0f/64.0f); } }        \
        __syncthreads();                                                             \
        { float stdv = sqrtf((redl[4]+redl[5]+redl[6]+redl[7]) * (1.0f/511.0f));     \
          xts[t] = a2s[t]/stdv; xts[t+256] = a2s[t+256]/stdv; }                      \
        __syncthreads();                                                             \
        _Pragma("unroll")                                                            \
        for (int e = 0; e < 2; ++e) {                                                \
            int idx = t + e*256; int bb = idx >> 6, j = idx & 63;                    \
            float acc = be[j];                                                       \
            _Pragma("unroll")                                                        \
            for (int k = 0; k < 64; ++k) acc += wTe[k*64+j] * xts[bb*64+k];          \
            htl[idx] = 1.0f/(1.0f+expf(-acc));                                       \
        }                                                                            \
        __syncthreads();                                                             \
        _Pragma("unroll")                                                            \
        for (int e = 0; e < 2; ++e) {                                                \
            int idx = t + e*256; int bb = idx >> 6, j = idx & 63;                    \
            float acc = bu[j] + bm[j];                                               \
            _Pragma("unroll")                                                        \
            for (int k = 0; k < 64; ++k)                                             \
                acc += wTu[k*64+j]*htl[bb*64+k] + wTm[k*64+j]*tauls[512 + bb*64+k];  \
            float tn = fmaxf(acc, 0.0f);                                             \
            if (c == 0 && bb == b) st_f(&tauws[(size_t)((K0+1) & 511) * 512 + idx], tn); \
            float scl = tn / sgls[bb];                                               \
            resB[idx] = make_float2(rr_[e]*scl, ri_[e]*scl);                         \
        }                                                                            \
        __syncthreads();                                                             \
        /* ======== Phase C: x += (resA*conj(P) + resB*conj(Q))/65536 ======== */    \
        float2 ac0 = make_float2(0.f,0.f), ac1 = make_float2(0.f,0.f);               \
        float2 ac2 = make_float2(0.f,0.f), ac3 = make_float2(0.f,0.f);               \
        _Pragma("unroll")                                                            \
        for (int j = 0; j < 8; ++j) {                                                \
            float2 ra = resA[b*64 + rbase + 8*j];                                    \
            float2 rb2 = resB[b*64 + rbase + 8*j];                                   \
            float4 pr = PRE_[j], pi = PIM_[j], qr = QRE_[j], qi = QIM_[j];           \
            ac0.x += ra.x*pr.x + ra.y*pi.x + rb2.x*qr.x + rb2.y*qi.x;                \
            ac0.y += ra.y*pr.x - ra.x*pi.x + rb2.y*qr.x - rb2.x*qi.x;                \
            ac1.x += ra.x*pr.y + ra.y*pi.y + rb2.x*qr.y + rb2.y*qi.y;                \
            ac1.y += ra.y*pr.y - ra.x*pi.y + rb2.y*qr.y - rb2.x*qi.y;                \
            ac2.x += ra.x*pr.z + ra.y*pi.z + rb2.x*qr.z + rb2.y*qi.z;                \
            ac2.y += ra.y*pr.z - ra.x*pi.z + rb2.y*qr.z - rb2.x*qi.z;                \
            ac3.x += ra.x*pr.w + ra.y*pi.w + rb2.x*qr.w + rb2.y*qi.w;                \
            ac3.y += ra.y*pr.w - ra.x*pi.w + rb2.y*qr.w - rb2.x*qi.w;                \
        }                                                                            \
        /* refill P bank with next window's Q block (P,Q dead after this) */         \
        PREF(PRE_, PIM_, nb1);                                                       \
        ac0.x += __shfl_xor(ac0.x, 32); ac0.y += __shfl_xor(ac0.y, 32);              \
        ac1.x += __shfl_xor(ac1.x, 32); ac1.y += __shfl_xor(ac1.y, 32);              \
        ac2.x += __shfl_xor(ac2.x, 32); ac2.y += __shfl_xor(ac2.y, 32);              \
        ac3.x += __shfl_xor(ac3.x, 32); ac3.y += __shfl_xor(ac3.y, 32);              \
        if ((t & 32) == 0) {                                                         \
            cpartC[wv][sub][0] = ac0; cpartC[wv][sub][1] = ac1;                      \
            cpartC[wv][sub][2] = ac2; cpartC[wv][sub][3] = ac3;                      \
        }                                                                            \
        tauls[t] = tnA0; tauls[t + 256] = tnA1;                                      \
        tauls[512 + t] = tnB0; tauls[512 + t + 256] = tnB1;                          \
        __syncthreads();                                                             \
        if (t < 128) {                                                               \
            int sl = t >> 2, kk = t & 3;                                             \
            float2 s0 = cpartC[0][sl][kk], s1 = cpartC[1][sl][kk];                   \
            float2 s2 = cpartC[2][sl][kk], s3 = cpartC[3][sl][kk];                   \
            float2 xv = x_l[t];                                                      \
            xv.x += (s0.x + s1.x + s2.x + s3.x) * (1.0f/65536.0f);                   \
            xv.y += (s0.y + s1.y + s2.y + s3.y) * (1.0f/65536.0f);                   \
            x_l[t] = xv;                                                             \
        }                                                                            \
    } while (0)

// soft threshold at iteration boundaries (gw & 255 == 255)
#define THR(GW) do {                                                                 \
        if ((((GW) & 255)) == 255) {                                                 \
            const unsigned itg = (unsigned)(((GW) >> 8) + 1);                        \
            float lm = 0.0f;                                                         \
            if (t < 128) { float2 xv = x_l[t]; lm = sqrtf(xv.x*xv.x + xv.y*xv.y); }  \
            lm = wmax64(lm);                                                         \
            if (lane == 0) redl[wv] = lm;                                            \
            __syncthreads();                                                         \
            if (t == 0)                                                              \
                st_u_rel(&pm_u[g], tagf(fmaxf(fmaxf(redl[0], redl[1]),               \
                                              fmaxf(redl[2], redl[3])), itg));       \
            float pv = 0.0f;                                                         \
            if (t < 64) {                                                            \
                unsigned u;                                                          \
                for (;;) {                                                           \
                    u = ld_u(&pm_u[t]);                                              \
                    if ((u & 0xFFu) == itg) break;                                   \
                    __builtin_amdgcn_s_sleep(1);                                     \
                }                                                                    \
                pv = __uint_as_float(u);                                             \
            }                                                                        \
            __builtin_amdgcn_fence(__ATOMIC_ACQUIRE, "agent");                       \
            pv = wmax64(pv);                                                         \
            if (t == 0) gmax[0] = pv;                                                \
            __syncthreads();                                                         \
            float m = gmax[0];                                                       \
            if (t < 128) {                                                           \
                float2 xv = x_l[t];                                                  \
                float ax = sqrtf(xv.x*xv.x + xv.y*xv.y);                             \
                float s = (ax > 0.0f) ? fmaxf(ax - 1e-3f * m, 0.0f) / ax : 0.0f;     \
                x_l[t] = make_float2(xv.x * s, xv.y * s);                            \
            }                                                                        \
            __syncthreads();                                                         \
        }                                                                            \
    } while (0)

    // flat window loop: 2560 windows, bank rotation period 3 (2559 = 3*853)
    #pragma unroll 1
    for (int gw = 0; gw < 2560; gw += 3) {
        WSTEP(gw, h0re, h0im, h1re, h1im, h2re, h2im); THR(gw);
        if (gw + 1 < 2560) { WSTEP(gw + 1, h2re, h2im, h0re, h0im, h1re, h1im); THR(gw + 1); }
        if (gw + 2 < 2560) { WSTEP(gw + 2, h1re, h1im, h2re, h2im, h0re, h0im); THR(gw + 2); }
    }

    // ---------------- output ----------------
    if (t < 128) out[b * 1024 + c * 128 + t] = x_l[t].x;
    for (int i = g * 8; i < g * 8 + 8; ++i) {
        for (int idx = t; idx < 512; idx += NT) {
            int bb = idx >> 6, w = idx & 63;
            out[8192 + bb * 32768 + i * 64 + w] = ld_f(&tauws[(size_t)i * 512 + bb * 64 + w]);
        }
    }
#undef WSTEP
#undef THR
#undef POLL8
#undef TCHK
#undef PREF
}

// Diagnostic: if a launch is rejected, stamp the error code into output-0.
__global__ void robii_diag_kernel(float* out, int code) {
    int i = blockIdx.x * blockDim.x + threadIdx.x;
    if (i < 8192) out[i] = 1.0e6f * (float)(1 + code);
}

extern "C" void kernel_launch(void* const* d_in, const int* in_sizes, int n_in,
                              void* d_out, int out_size, void* d_ws, size_t ws_size,
                              hipStream_t stream) {
    (void)in_sizes; (void)n_in; (void)out_size; (void)ws_size;
    const float* y_re     = (const float*)d_in[0];
    const float* y_im     = (const float*)d_in[1];
    const float* H_re     = (const float*)d_in[2];
    const float* H_im     = (const float*)d_in[3];
    const float* estep_w  = (const float*)d_in[4];
    const float* estep_b  = (const float*)d_in[5];
    const float* update_w = (const float*)d_in[6];
    const float* update_b = (const float*)d_in[7];
    const float* memory_w = (const float*)d_in[8];
    const float* memory_b = (const float*)d_in[9];
    float* outp = (float*)d_out;
    float* wsp  = (float*)d_ws;

    hipLaunchKernelGGL(gram_kernel, dim3(256), dim3(256), 0, stream,
                       H_re, H_im, (unsigned*)wsp);
    hipLaunchKernelGGL(robii_gram, dim3(NWG), dim3(NT), 0, stream,
                       y_re, y_im, H_re, H_im, estep_w, estep_b,
                       update_w, update_b, memory_w, memory_b, outp, wsp);
    hipError_t e = hipGetLastError();
    if (e != hipSuccess) {
        hipLaunchKernelGGL(robii_diag_kernel, dim3(32), dim3(256), 0, stream,
                           outp, (int)e);
    }
}

// Round 16
// 70447.418 us; speedup vs baseline: 1.1706x; 1.1706x over previous
//
#include <hip/hip_runtime.h>
#include <math.h>

#define NT  256
#define NWG 64
#define SCOPE_AG __HIP_MEMORY_SCOPE_AGENT
typedef unsigned long long ull;

// ---------- agent-scope (coherence-point) atomic helpers ----------
__device__ __forceinline__ float ld_f(const float* p) {
    return __hip_atomic_load(p, __ATOMIC_RELAXED, SCOPE_AG);
}
__device__ __forceinline__ void st_f(float* p, float v) {
    __hip_atomic_store(p, v, __ATOMIC_RELAXED, SCOPE_AG);
}
__device__ __forceinline__ unsigned ld_u(const unsigned* p) {
    return __hip_atomic_load(p, __ATOMIC_RELAXED, SCOPE_AG);
}
__device__ __forceinline__ void st_u_rel(unsigned* p, unsigned v) {
    __hip_atomic_store(p, v, __ATOMIC_RELEASE, SCOPE_AG);
}
__device__ __forceinline__ ull ld_u64(const ull* p) {
    return __hip_atomic_load(p, __ATOMIC_RELAXED, SCOPE_AG);
}
__device__ __forceinline__ void st_u64(ull* p, ull v) {
    __hip_atomic_store(p, v, __ATOMIC_RELAXED, SCOPE_AG);
}

// async global->LDS, 16B per lane; LDS dest = wave-uniform base + lane*16
__device__ __forceinline__ void glds16(const float* g, float* l) {
    __builtin_amdgcn_global_load_lds(
        (const __attribute__((address_space(1))) unsigned*)g,
        (__attribute__((address_space(3))) unsigned*)l,
        16, 0, 0);
}

// mantissa tag: low 8 bits of the float carry the epoch tag (noise ~2^-17 rel)
__device__ __forceinline__ unsigned tagf(float v, unsigned tg) {
    return (__float_as_uint(v) & 0xFFFFFF00u) | tg;
}
__device__ __forceinline__ ull pack2(float lo, float hi, unsigned tg) {
    return ((ull)tagf(hi, tg) << 32) | (ull)tagf(lo, tg);
}
// bf16 pack/unpack (round-to-nearest-even); even -> low16
__device__ __forceinline__ unsigned bf16pack(float even, float odd) {
    unsigned ua = __float_as_uint(even); ua += 0x7FFFu + ((ua >> 16) & 1u);
    unsigned ub = __float_as_uint(odd);  ub += 0x7FFFu + ((ub >> 16) & 1u);
    return (ua >> 16) | (ub & 0xFFFF0000u);
}
__device__ __forceinline__ float bf16lo(unsigned w) { return __uint_as_float(w << 16); }
__device__ __forceinline__ float bf16hi(unsigned w) { return __uint_as_float(w & 0xFFFF0000u); }

__device__ __forceinline__ float wsum64(float v) {
    #pragma unroll
    for (int m = 1; m < 64; m <<= 1) v += __shfl_xor(v, m);
    return v;
}
__device__ __forceinline__ float wmax64(float v) {
    #pragma unroll
    for (int m = 1; m < 64; m <<= 1) v = fmaxf(v, __shfl_xor(v, m));
    return v;
}

// ================= ws layout (floats) =================
//   Ttab:   u32[256 pair][64 w][64 w']      @ 0         (1,048,576 floats; bf16x2)
//   partuw: ull[2 par][2 set][512][8 c]     @ 1,048,576 (32,768 floats)
//   tauws:  float[512 blk][512 (b,w)]       @ 1,081,344 (262,144 floats)
//   pm_u:   unsigned[64]                    @ 1,343,488
// total 5,374,208 B (fit proven by R13/R15 runs)
#define PART_OFF 1048576
#define TAU_OFF  1081344
#define PM_OFF   1343488

// ---------------- Gram precompute: T[pair][w][w'] = sum_d conj(A[w',d])*B[w,d] ----------------
__launch_bounds__(256, 1)
__global__ void gram_kernel(const float* __restrict__ H_re, const float* __restrict__ H_im,
                            unsigned* __restrict__ Ttab) {
    __shared__ float2 Als[64 * 65];
    __shared__ float2 Bls[64 * 65];
    const int i = blockIdx.x;            // pair index: blocks 2i, 2i+1
    const int t = threadIdx.x;
    const int w = t & 63;
    const int wp0 = (t >> 6) * 16;
    const size_t baseA = (size_t)(2 * i) * 65536;
    const size_t baseB = baseA + 65536;
    float2 acc[16];
    #pragma unroll
    for (int s = 0; s < 16; ++s) acc[s] = make_float2(0.0f, 0.0f);

    for (int ch = 0; ch < 16; ++ch) {
        __syncthreads();
        for (int k = t; k < 4096; k += 256) {
            int r = k >> 6, d = k & 63;
            size_t off = (size_t)r * 1024 + ch * 64 + d;
            Als[r * 65 + d] = make_float2(H_re[baseA + off], H_im[baseA + off]);
            Bls[r * 65 + d] = make_float2(H_re[baseB + off], H_im[baseB + off]);
        }
        __syncthreads();
        #pragma unroll
        for (int s = 0; s < 16; ++s) {
            int wp = wp0 + s;
            float ar = 0.0f, ai = 0.0f;
            #pragma unroll 8
            for (int d = 0; d < 64; ++d) {
                float2 a = Als[wp * 65 + d];
                float2 bb = Bls[w * 65 + d];
                ar += a.x * bb.x + a.y * bb.y;
                ai += a.x * bb.y - a.y * bb.x;
            }
            acc[s].x += ar; acc[s].y += ai;
        }
    }
    #pragma unroll
    for (int s = 0; s < 16; ++s)
        Ttab[(size_t)i * 4096 + w * 64 + (wp0 + s)] = bf16pack(acc[s].x, acc[s].y);
}

// ---------------- main kernel: 2 blocks per exchange; H[K0] in LDS, H[K1] in VGPRs ----------------
__launch_bounds__(NT, 1)
__global__ void robii_gram(
    const float* __restrict__ y_re, const float* __restrict__ y_im,
    const float* __restrict__ H_re, const float* __restrict__ H_im,
    const float* __restrict__ estep_w, const float* __restrict__ estep_b,
    const float* __restrict__ update_w, const float* __restrict__ update_b,
    const float* __restrict__ memory_w, const float* __restrict__ memory_b,
    float* __restrict__ out, float* __restrict__ ws)
{
    __shared__ float wTe[4096], wTu[4096], wTm[4096];
    __shared__ float be[64], bu[64], bm[64];
    __shared__ float a2s[512], xts[512], htl[512];
    __shared__ float redl[8], sgls[8], gmax[1];
    __shared__ float tauls[1024];          // [2 slot][512 (b,w)] prev-iter tau, current window
    __shared__ float2 resA[512], resB[512];
    __shared__ unsigned Tls[4160];         // [64][65] bf16x2 Gram tile (padded)
    __shared__ float2 cpartC[4][32][4];
    __shared__ float2 x_l[128];
    __shared__ float Lre[8192], Lim[8192]; // H[K0] bank: [32 chunk][256], chunk=(j*4+wv), lane-linear

    const int g = blockIdx.x, t = threadIdx.x;
    const int c = g & 7;
    const int b = g >> 3;
    const int lane = t & 63, wv = t >> 6;
    const int sub = t & 31;
    const int rbase = t >> 5;

    unsigned* Ttab   = (unsigned*)ws;
    ull*      partuw = (ull*)(ws + PART_OFF);
    float*    tauws  = ws + TAU_OFF;
    unsigned* pm_u   = (unsigned*)(ws + PM_OFF);

    // ---------------- init ----------------
    for (int i = t; i < 4096; i += NT) {
        int j = i >> 6, k = i & 63;
        wTe[k * 64 + j] = estep_w[i];
        wTu[k * 64 + j] = update_w[i];
        wTm[k * 64 + j] = memory_w[i];
    }
    if (t < 64) { be[t] = estep_b[t]; bu[t] = update_b[t]; bm[t] = memory_b[t]; }
    if (t < 128) x_l[t] = make_float2(0.0f, 0.0f);
    for (int i = t; i < 1024; i += NT) tauls[i] = 1.0f;
    for (int i = t; i < 4096; i += NT) st_f(&tauws[g * 4096 + i], 1.0f);

    // init sync (tag 255): publishes tau init
    __syncthreads();
    if (t == 0) st_u_rel(&pm_u[g], tagf(1.0f, 255u));
    if (t < 64) {
        while ((ld_u(&pm_u[t]) & 0xFFu) != 255u) __builtin_amdgcn_s_sleep(1);
    }
    __builtin_amdgcn_fence(__ATOMIC_ACQUIRE, "agent");
    __syncthreads();

    const size_t hcol = (size_t)c * 128 + (size_t)sub * 4;
    float4 hVre[8], hVim[8];               // H[K1] bank (64 VGPRs)
    const float4* Lre4 = (const float4*)Lre;
    const float4* Lim4 = (const float4*)Lim;

#define PREF(DRE, DIM_, BLKN) do {                                                   \
        const float* _pr = H_re + ((size_t)(BLKN) * 64 + rbase) * 1024 + hcol;       \
        const float* _pi = H_im + ((size_t)(BLKN) * 64 + rbase) * 1024 + hcol;       \
        _Pragma("unroll")                                                            \
        for (int _j = 0; _j < 8; ++_j) {                                             \
            DRE[_j]  = *(const float4*)(_pr + (size_t)_j * 8192);                    \
            DIM_[_j] = *(const float4*)(_pi + (size_t)_j * 8192);                    \
        }                                                                            \
    } while (0)

// async-load L bank <- H[BLKN]: per (j, re/im), wave wv's lanes write chunk (j*4+wv)
#define LOADL(BLKN) do {                                                             \
        const float* _pr = H_re + ((size_t)(BLKN) * 64 + rbase) * 1024 + hcol;       \
        const float* _pi = H_im + ((size_t)(BLKN) * 64 + rbase) * 1024 + hcol;       \
        _Pragma("unroll")                                                            \
        for (int _j = 0; _j < 8; ++_j) {                                             \
            glds16(_pr + (size_t)_j * 8192, &Lre[(_j * 4 + wv) * 256]);              \
            glds16(_pi + (size_t)_j * 8192, &Lim[(_j * 4 + wv) * 256]);              \
        }                                                                            \
    } while (0)

    // prologue: L <- H[0], V <- H[1]
    LOADL(0);
    PREF(hVre, hVim, 1);

#define TCHK(V) (((((unsigned)(V)) & 0xFFu) ^ tg) | ((((unsigned)((V) >> 32)) & 0xFFu) ^ tg))

#define POLL8(PB, ZR, ZI) do {                                                       \
        ull v0,v1,v2,v3,v4,v5,v6,v7;                                                 \
        bool ok = false;                                                             \
        while (!ok) {                                                                \
            v0=ld_u64((PB)+0); v1=ld_u64((PB)+1); v2=ld_u64((PB)+2); v3=ld_u64((PB)+3); \
            v4=ld_u64((PB)+4); v5=ld_u64((PB)+5); v6=ld_u64((PB)+6); v7=ld_u64((PB)+7); \
            unsigned mm = TCHK(v0)|TCHK(v1)|TCHK(v2)|TCHK(v3)                        \
                        | TCHK(v4)|TCHK(v5)|TCHK(v6)|TCHK(v7);                       \
            ok = (mm == 0u);                                                         \
            if (!ok) __builtin_amdgcn_s_sleep(1);                                    \
        }                                                                            \
        ZR = __uint_as_float((unsigned)v0) + __uint_as_float((unsigned)v1)           \
           + __uint_as_float((unsigned)v2) + __uint_as_float((unsigned)v3)           \
           + __uint_as_float((unsigned)v4) + __uint_as_float((unsigned)v5)           \
           + __uint_as_float((unsigned)v6) + __uint_as_float((unsigned)v7);          \
        ZI = __uint_as_float((unsigned)(v0>>32)) + __uint_as_float((unsigned)(v1>>32)) \
           + __uint_as_float((unsigned)(v2>>32)) + __uint_as_float((unsigned)(v3>>32)) \
           + __uint_as_float((unsigned)(v4>>32)) + __uint_as_float((unsigned)(v5>>32)) \
           + __uint_as_float((unsigned)(v6>>32)) + __uint_as_float((unsigned)(v7>>32)); \
    } while (0)

    // flat window loop: 2560 windows (10 iters x 256), 2 blocks each
    #pragma unroll 1
    for (int gw = 0; gw < 2560; ++gw) {
        const int par = gw & 1;
        const int K0 = (2 * gw) & 511;
        const unsigned tg = (unsigned)(gw + 1) & 0xFFu;
        __syncthreads();   // x_l boundary

        float2 xr0 = x_l[sub * 4 + 0], xr1 = x_l[sub * 4 + 1];
        float2 xr2 = x_l[sub * 4 + 2], xr3 = x_l[sub * 4 + 3];

        // ---- Phase A-V: zpre_K1 partials from V bank (set 1) ----
        #pragma unroll
        for (int j = 0; j < 8; ++j) {
            float4 qr = hVre[j], qi = hVim[j];
            float ur, ui;
            ur  = xr0.x*qr.x - xr0.y*qi.x;  ui  = xr0.x*qi.x + xr0.y*qr.x;
            ur += xr1.x*qr.y - xr1.y*qi.y;  ui += xr1.x*qi.y + xr1.y*qr.y;
            ur += xr2.x*qr.z - xr2.y*qi.z;  ui += xr2.x*qi.z + xr2.y*qr.z;
            ur += xr3.x*qr.w - xr3.y*qi.w;  ui += xr3.x*qi.w + xr3.y*qr.w;
            #pragma unroll
            for (int m = 1; m < 32; m <<= 1) {
                ur += __shfl_xor(ur, m); ui += __shfl_xor(ui, m);
            }
            if (sub == 0)
                st_u64(&partuw[((size_t)(par * 2 + 1) * 512 + b * 64 + rbase + 8 * j) * 8 + c],
                       pack2(ur, ui, tg));
        }

        // ---- ensure L bank (async global_load_lds issued last window) landed ----
        asm volatile("s_waitcnt vmcnt(0)" ::: "memory");

        // ---- Phase A-L: z_K0 partials from L bank in LDS (set 0) ----
        #pragma unroll
        for (int j = 0; j < 8; ++j) {
            float4 pr = Lre4[(j * 4 + wv) * 64 + lane];
            float4 pi = Lim4[(j * 4 + wv) * 64 + lane];
            float sr, si;
            sr  = xr0.x*pr.x - xr0.y*pi.x;  si  = xr0.x*pi.x + xr0.y*pr.x;
            sr += xr1.x*pr.y - xr1.y*pi.y;  si += xr1.x*pi.y + xr1.y*pr.y;
            sr += xr2.x*pr.z - xr2.y*pi.z;  si += xr2.x*pi.z + xr2.y*pr.z;
            sr += xr3.x*pr.w - xr3.y*pi.w;  si += xr3.x*pi.w + xr3.y*pr.w;
            #pragma unroll
            for (int m = 1; m < 32; m <<= 1) {
                sr += __shfl_xor(sr, m); si += __shfl_xor(si, m);
            }
            if (sub == 0)
                st_u64(&partuw[((size_t)(par * 2 + 0) * 512 + b * 64 + rbase + 8 * j) * 8 + c],
                       pack2(sr, si, tg));
        }

        // ---- overlap zone: Gram tile, tau(next window), y ----
        int nb0 = (2 * gw + 2) & 511, nb1 = (2 * gw + 3) & 511;
        for (int q = t; q < 4096; q += NT)
            Tls[(q >> 6) * 65 + (q & 63)] = Ttab[(size_t)(gw & 255) * 4096 + q];
        float tnA0 = ld_f(&tauws[nb0 * 512 + t]);
        float tnA1 = ld_f(&tauws[nb0 * 512 + t + 256]);
        float tnB0 = ld_f(&tauws[nb1 * 512 + t]);
        float tnB1 = ld_f(&tauws[nb1 * 512 + t + 256]);
        float y0r[2], y0i[2], y1r[2], y1i[2];
        #pragma unroll
        for (int e = 0; e < 2; ++e) {
            int idx = t + e * 256; int bb = idx >> 6, w = idx & 63;
            int n0 = K0 * 64 + w, n1 = n0 + 64;
            if (n0 < 16384) { y0r[e] = y_re[bb*16384+n0];       y0i[e] = y_im[bb*16384+n0]; }
            else            { y0r[e] = y_re[bb*16384+n0-16384]; y0i[e] = -y_im[bb*16384+n0-16384]; }
            if (n1 < 16384) { y1r[e] = y_re[bb*16384+n1];       y1i[e] = y_im[bb*16384+n1]; }
            else            { y1r[e] = y_re[bb*16384+n1-16384]; y1i[e] = -y_im[bb*16384+n1-16384]; }
        }

        // ---- poll both sets (one exchange for two blocks) ----
        float zpr[2], zpi[2], rr_[2], ri_[2];
        #pragma unroll
        for (int e = 0; e < 2; ++e) {
            int idx = t + e * 256;
            float zr, zi;
            POLL8(partuw + ((size_t)(par * 2 + 0) * 512 + idx) * 8, zr, zi);
            POLL8(partuw + ((size_t)(par * 2 + 1) * 512 + idx) * 8, zpr[e], zpi[e]);
            rr_[e] = y0r[e] - zr; ri_[e] = y0i[e] - zi;
            a2s[idx] = rr_[e] * rr_[e] + ri_[e] * ri_[e];
        }

        // ======== sub-step K0: stats + MLP (all b) + resid ========
        __syncthreads();
        { float s_ = wsum64(a2s[t] + a2s[t + 256]);
          if (lane == 0) redl[wv] = s_; }
        __syncthreads();
        { float mean = (redl[0]+redl[1]+redl[2]+redl[3]) * (1.0f/512.0f);
          float d0 = a2s[t]-mean, d1 = a2s[t+256]-mean;
          float s2_ = wsum64(d0*d0 + d1*d1);
          float sgA = wsum64(a2s[wv*64 + lane]);
          float sgB = wsum64(a2s[(wv+4)*64 + lane]);
          if (lane == 0) { redl[4+wv] = s2_;
              sgls[wv] = sgA*(1.0f/64.0f); sgls[wv+4] = sgB*(1.0f/64.0f); } }
        __syncthreads();
        { float stdv = sqrtf((redl[4]+redl[5]+redl[6]+redl[7]) * (1.0f/511.0f));
          xts[t] = a2s[t]/stdv; xts[t+256] = a2s[t+256]/stdv; }
        __syncthreads();
        #pragma unroll
        for (int e = 0; e < 2; ++e) {
            int idx = t + e*256; int bb = idx >> 6, j = idx & 63;
            float acc = be[j];
            #pragma unroll
            for (int k = 0; k < 64; ++k) acc += wTe[k*64+j] * xts[bb*64+k];
            htl[idx] = 1.0f/(1.0f+expf(-acc));
        }
        __syncthreads();
        #pragma unroll
        for (int e = 0; e < 2; ++e) {
            int idx = t + e*256; int bb = idx >> 6, j = idx & 63;
            float acc = bu[j] + bm[j];
            #pragma unroll
            for (int k = 0; k < 64; ++k)
                acc += wTu[k*64+j]*htl[bb*64+k] + wTm[k*64+j]*tauls[bb*64+k];
            float tn = fmaxf(acc, 0.0f);
            if (c == 0 && bb == b) st_f(&tauws[(size_t)K0 * 512 + idx], tn);
            float scl = tn / sgls[bb];
            resA[idx] = make_float2(rr_[e]*scl, ri_[e]*scl);
        }
        __syncthreads();

        // ======== Gram correction -> z_{K0+1}, then sub-step K0+1 ========
        #pragma unroll
        for (int e = 0; e < 2; ++e) {
            int idx = t + e*256; int bb = idx >> 6, w = idx & 63;
            float cr = 0.0f, ci = 0.0f;
            #pragma unroll 8
            for (int wp = 0; wp < 64; ++wp) {
                float2 rs = resA[bb*64 + wp];
                unsigned gw2 = Tls[w*65 + wp];
                float gr = bf16lo(gw2), gi = bf16hi(gw2);
                cr += rs.x*gr - rs.y*gi;
                ci += rs.x*gi + rs.y*gr;
            }
            float z1r = zpr[e] + cr * (1.0f/65536.0f);
            float z1i = zpi[e] + ci * (1.0f/65536.0f);
            rr_[e] = y1r[e] - z1r; ri_[e] = y1i[e] - z1i;
            a2s[idx] = rr_[e]*rr_[e] + ri_[e]*ri_[e];
        }
        __syncthreads();
        { float s_ = wsum64(a2s[t] + a2s[t + 256]);
          if (lane == 0) redl[wv] = s_; }
        __syncthreads();
        { float mean = (redl[0]+redl[1]+redl[2]+redl[3]) * (1.0f/512.0f);
          float d0 = a2s[t]-mean, d1 = a2s[t+256]-mean;
          float s2_ = wsum64(d0*d0 + d1*d1);
          float sgA = wsum64(a2s[wv*64 + lane]);
          float sgB = wsum64(a2s[(wv+4)*64 + lane]);
          if (lane == 0) { redl[4+wv] = s2_;
              sgls[wv] = sgA*(1.0f/64.0f); sgls[wv+4] = sgB*(1.0f/64.0f); } }
        __syncthreads();
        { float stdv = sqrtf((redl[4]+redl[5]+redl[6]+redl[7]) * (1.0f/511.0f));
          xts[t] = a2s[t]/stdv; xts[t+256] = a2s[t+256]/stdv; }
        __syncthreads();
        #pragma unroll
        for (int e = 0; e < 2; ++e) {
            int idx = t + e*256; int bb = idx >> 6, j = idx & 63;
            float acc = be[j];
            #pragma unroll
            for (int k = 0; k < 64; ++k) acc += wTe[k*64+j] * xts[bb*64+k];
            htl[idx] = 1.0f/(1.0f+expf(-acc));
        }
        __syncthreads();
        #pragma unroll
        for (int e = 0; e < 2; ++e) {
            int idx = t + e*256; int bb = idx >> 6, j = idx & 63;
            float acc = bu[j] + bm[j];
            #pragma unroll
            for (int k = 0; k < 64; ++k)
                acc += wTu[k*64+j]*htl[bb*64+k] + wTm[k*64+j]*tauls[512 + bb*64+k];
            float tn = fmaxf(acc, 0.0f);
            if (c == 0 && bb == b) st_f(&tauws[(size_t)((K0+1) & 511) * 512 + idx], tn);
            float scl = tn / sgls[bb];
            resB[idx] = make_float2(rr_[e]*scl, ri_[e]*scl);
        }
        __syncthreads();

        // ======== Phase C: x += (resA*conj(L) + resB*conj(V))/65536 ========
        float2 ac0 = make_float2(0.f,0.f), ac1 = make_float2(0.f,0.f);
        float2 ac2 = make_float2(0.f,0.f), ac3 = make_float2(0.f,0.f);
        #pragma unroll
        for (int j = 0; j < 8; ++j) {
            float2 ra  = resA[b*64 + rbase + 8*j];
            float2 rb2 = resB[b*64 + rbase + 8*j];
            float4 pr = Lre4[(j * 4 + wv) * 64 + lane];
            float4 pi = Lim4[(j * 4 + wv) * 64 + lane];
            float4 qr = hVre[j], qi = hVim[j];
            ac0.x += ra.x*pr.x + ra.y*pi.x + rb2.x*qr.x + rb2.y*qi.x;
            ac0.y += ra.y*pr.x - ra.x*pi.x + rb2.y*qr.x - rb2.x*qi.x;
            ac1.x += ra.x*pr.y + ra.y*pi.y + rb2.x*qr.y + rb2.y*qi.y;
            ac1.y += ra.y*pr.y - ra.x*pi.y + rb2.y*qr.y - rb2.x*qi.y;
            ac2.x += ra.x*pr.z + ra.y*pi.z + rb2.x*qr.z + rb2.y*qi.z;
            ac2.y += ra.y*pr.z - ra.x*pi.z + rb2.y*qr.z - rb2.x*qi.z;
            ac3.x += ra.x*pr.w + ra.y*pi.w + rb2.x*qr.w + rb2.y*qi.w;
            ac3.y += ra.y*pr.w - ra.x*pi.w + rb2.y*qr.w - rb2.x*qi.w;
        }
        ac0.x += __shfl_xor(ac0.x, 32); ac0.y += __shfl_xor(ac0.y, 32);
        ac1.x += __shfl_xor(ac1.x, 32); ac1.y += __shfl_xor(ac1.y, 32);
        ac2.x += __shfl_xor(ac2.x, 32); ac2.y += __shfl_xor(ac2.y, 32);
        ac3.x += __shfl_xor(ac3.x, 32); ac3.y += __shfl_xor(ac3.y, 32);
        if ((t & 32) == 0) {
            cpartC[wv][sub][0] = ac0; cpartC[wv][sub][1] = ac1;
            cpartC[wv][sub][2] = ac2; cpartC[wv][sub][3] = ac3;
        }
        tauls[t] = tnA0; tauls[t + 256] = tnA1;
        tauls[512 + t] = tnB0; tauls[512 + t + 256] = tnB1;
        __syncthreads();
        if (t < 128) {
            int sl = t >> 2, kk = t & 3;
            float2 s0 = cpartC[0][sl][kk], s1 = cpartC[1][sl][kk];
            float2 s2 = cpartC[2][sl][kk], s3 = cpartC[3][sl][kk];
            float2 xv = x_l[t];
            xv.x += (s0.x + s1.x + s2.x + s3.x) * (1.0f/65536.0f);
            xv.y += (s0.y + s1.y + s2.y + s3.y) * (1.0f/65536.0f);
            x_l[t] = xv;
        }
        __syncthreads();

        // ---- post-C: issue next window's bank loads (L async->LDS, V->regs) ----
        // per-thread safety: each thread's L slots are read only by itself, and its
        // C-phase ds_reads completed (values consumed) before these issue.
        LOADL(nb0);
        PREF(hVre, hVim, nb1);

        // ---- soft threshold at iteration boundary ----
        if ((gw & 255) == 255) {
            const unsigned itg = (unsigned)((gw >> 8) + 1);
            float lm = 0.0f;
            if (t < 128) { float2 xv = x_l[t]; lm = sqrtf(xv.x*xv.x + xv.y*xv.y); }
            lm = wmax64(lm);
            if (lane == 0) redl[wv] = lm;
            __syncthreads();
            if (t == 0)
                st_u_rel(&pm_u[g], tagf(fmaxf(fmaxf(redl[0], redl[1]),
                                              fmaxf(redl[2], redl[3])), itg));
            float pv = 0.0f;
            if (t < 64) {
                unsigned u;
                for (;;) {
                    u = ld_u(&pm_u[t]);
                    if ((u & 0xFFu) == itg) break;
                    __builtin_amdgcn_s_sleep(1);
                }
                pv = __uint_as_float(u);
            }
            __builtin_amdgcn_fence(__ATOMIC_ACQUIRE, "agent");
            pv = wmax64(pv);
            if (t == 0) gmax[0] = pv;
            __syncthreads();
            float m = gmax[0];
            if (t < 128) {
                float2 xv = x_l[t];
                float ax = sqrtf(xv.x*xv.x + xv.y*xv.y);
                float s = (ax > 0.0f) ? fmaxf(ax - 1e-3f * m, 0.0f) / ax : 0.0f;
                x_l[t] = make_float2(xv.x * s, xv.y * s);
            }
            __syncthreads();
        }
    } // gw

    // ---------------- output ----------------
    if (t < 128) out[b * 1024 + c * 128 + t] = x_l[t].x;
    for (int i = g * 8; i < g * 8 + 8; ++i) {
        for (int idx = t; idx < 512; idx += NT) {
            int bb = idx >> 6, w = idx & 63;
            out[8192 + bb * 32768 + i * 64 + w] = ld_f(&tauws[(size_t)i * 512 + bb * 64 + w]);
        }
    }
#undef POLL8
#undef TCHK
#undef LOADL
#undef PREF
}

// Diagnostic: if a launch is rejected, stamp the error code into output-0.
__global__ void robii_diag_kernel(float* out, int code) {
    int i = blockIdx.x * blockDim.x + threadIdx.x;
    if (i < 8192) out[i] = 1.0e6f * (float)(1 + code);
}

extern "C" void kernel_launch(void* const* d_in, const int* in_sizes, int n_in,
                              void* d_out, int out_size, void* d_ws, size_t ws_size,
                              hipStream_t stream) {
    (void)in_sizes; (void)n_in; (void)out_size; (void)ws_size;
    const float* y_re     = (const float*)d_in[0];
    const float* y_im     = (const float*)d_in[1];
    const float* H_re     = (const float*)d_in[2];
    const float* H_im     = (const float*)d_in[3];
    const float* estep_w  = (const float*)d_in[4];
    const float* estep_b  = (const float*)d_in[5];
    const float* update_w = (const float*)d_in[6];
    const float* update_b = (const float*)d_in[7];
    const float* memory_w = (const float*)d_in[8];
    const float* memory_b = (const float*)d_in[9];
    float* outp = (float*)d_out;
    float* wsp  = (float*)d_ws;

    hipLaunchKernelGGL(gram_kernel, dim3(256), dim3(256), 0, stream,
                       H_re, H_im, (unsigned*)wsp);
    hipLaunchKernelGGL(robii_gram, dim3(NWG), dim3(NT), 0, stream,
                       y_re, y_im, H_re, H_im, estep_w, estep_b,
                       update_w, update_b, memory_w, memory_b, outp, wsp);
    hipError_t e = hipGetLastError();
    if (e != hipSuccess) {
        hipLaunchKernelGGL(robii_diag_kernel, dim3(32), dim3(256), 0, stream,
                           outp, (int)e);
    }
}

// Round 17
// 40900.021 us; speedup vs baseline: 2.0162x; 1.7224x over previous
//
#include <hip/hip_runtime.h>
#include <math.h>

#define NT  256
#define NWG 64
#define SCOPE_AG __HIP_MEMORY_SCOPE_AGENT
typedef unsigned long long ull;

// ---------- agent-scope (coherence-point) atomic helpers ----------
__device__ __forceinline__ float ld_f(const float* p) {
    return __hip_atomic_load(p, __ATOMIC_RELAXED, SCOPE_AG);
}
__device__ __forceinline__ void st_f(float* p, float v) {
    __hip_atomic_store(p, v, __ATOMIC_RELAXED, SCOPE_AG);
}
__device__ __forceinline__ unsigned ld_u(const unsigned* p) {
    return __hip_atomic_load(p, __ATOMIC_RELAXED, SCOPE_AG);
}
__device__ __forceinline__ void st_u_rel(unsigned* p, unsigned v) {
    __hip_atomic_store(p, v, __ATOMIC_RELEASE, SCOPE_AG);
}
__device__ __forceinline__ ull ld_u64(const ull* p) {
    return __hip_atomic_load(p, __ATOMIC_RELAXED, SCOPE_AG);
}
__device__ __forceinline__ void st_u64(ull* p, ull v) {
    __hip_atomic_store(p, v, __ATOMIC_RELAXED, SCOPE_AG);
}

// mantissa tag: low 8 bits of the float carry the epoch tag (noise ~2^-17 rel)
__device__ __forceinline__ unsigned tagf(float v, unsigned tg) {
    return (__float_as_uint(v) & 0xFFFFFF00u) | tg;
}
__device__ __forceinline__ ull pack2(float lo, float hi, unsigned tg) {
    return ((ull)tagf(hi, tg) << 32) | (ull)tagf(lo, tg);
}

__device__ __forceinline__ float wsum64(float v) {
    #pragma unroll
    for (int m = 1; m < 64; m <<= 1) v += __shfl_xor(v, m);
    return v;
}
__device__ __forceinline__ float wmax64(float v) {
    #pragma unroll
    for (int m = 1; m < 64; m <<= 1) v = fmaxf(v, __shfl_xor(v, m));
    return v;
}

// ws layout (floats) — total 278,592 floats = 1,114,368 B (proven-safe):
//   partuw: ull[2 par][512 (b,w)][8 c]   @ 0       (16384 floats)
//           each u64 = two mantissa-tagged floats (re lo, im hi)
//           tag = (iter*512+blk+1) & 0xFF
//   tauws:  float[512 blk][8 b][64 w]    @ 16384   (262144 floats)
//   pm_u:   unsigned[64]                 @ 278528  (tagged floats; tag=iter+1, init=255)

__launch_bounds__(NT, 1)
__global__ void robii_kernel(
    const float* __restrict__ y_re, const float* __restrict__ y_im,
    const float* __restrict__ H_re, const float* __restrict__ H_im,
    const float* __restrict__ estep_w, const float* __restrict__ estep_b,
    const float* __restrict__ update_w, const float* __restrict__ update_b,
    const float* __restrict__ memory_w, const float* __restrict__ memory_b,
    float* __restrict__ out, float* __restrict__ ws)
{
    __shared__ float wTe[4096], wTu[4096], wTm[4096];  // transposed: wT[k*64+j] = w[j][k]
    __shared__ float be[64], bu[64], bm[64];
    __shared__ float a2s[512];
    __shared__ float redl[8];
    __shared__ float gmax[1];
    __shared__ float2 rown[64];
    __shared__ float xts[64], hts[64], taurow[64];
    __shared__ float2 resid[64];
    __shared__ float2 cpartC[4][32][4];   // Phase-C scratch; aliased as MLP partials
    __shared__ float2 x_l[128];     // this WG's x[b, c*128 .. c*128+127]

    float* mpartf = (float*)cpartC;  // [4][64] floats (time-shared with Phase C)

    const int g = blockIdx.x, t = threadIdx.x;
    const int c = g & 7;        // d-chunk owned
    const int b = g >> 3;       // batch owned
    const int lane = t & 63, wv = t >> 6;
    const int sub = t & 31;     // column slice (4 floats)
    const int rbase = t >> 5;   // row group 0..7 (rows rbase+8j)

    ull*      partuw = (ull*)ws;                 // [2][512][8] u64
    float*    tauws  = ws + 16384;               // [512][8][64]
    unsigned* pm_u   = (unsigned*)(ws + 278528); // [64] tagged floats

    // ---------------- init ----------------
    for (int i = t; i < 4096; i += NT) {
        int j = i >> 6, k = i & 63;
        wTe[k * 64 + j] = estep_w[i];
        wTu[k * 64 + j] = update_w[i];
        wTm[k * 64 + j] = memory_w[i];
    }
    if (t < 64) { be[t] = estep_b[t]; bu[t] = update_b[t]; bm[t] = memory_b[t]; taurow[t] = 1.0f; }
    if (t < 128) x_l[t] = make_float2(0.0f, 0.0f);
    for (int i = t; i < 4096; i += NT) st_f(&tauws[g * 4096 + i], 1.0f);

    // init sync via tagged pm (tag 255): publishes tau init.
    __syncthreads();                              // drains this WG's tau stores
    if (t == 0) st_u_rel(&pm_u[g], tagf(1.0f, 255u));
    if (t < 64) {
        while ((ld_u(&pm_u[t]) & 0xFFu) != 255u) __builtin_amdgcn_s_sleep(1);
    }
    __builtin_amdgcn_fence(__ATOMIC_ACQUIRE, "agent");
    __syncthreads();

    const size_t hcol = (size_t)c * 128 + (size_t)sub * 4;

    // H double-buffer register banks
    float4 hAre[8], hAim[8], hBre[8], hBim[8];

#define PREF(DRE, DIM_, BLKN) do {                                                   \
        const float* _pr = H_re + ((size_t)(BLKN) * 64 + rbase) * 1024 + hcol;       \
        const float* _pi = H_im + ((size_t)(BLKN) * 64 + rbase) * 1024 + hcol;       \
        _Pragma("unroll")                                                            \
        for (int _j = 0; _j < 8; ++_j) {                                             \
            DRE[_j]  = *(const float4*)(_pr + (size_t)_j * 8192);                    \
            DIM_[_j] = *(const float4*)(_pi + (size_t)_j * 8192);                    \
        }                                                                            \
    } while (0)

    PREF(hAre, hAim, 0);   // prologue: bank A <- block 0

#define TCHK(V) (((((unsigned)(V)) & 0xFFu) ^ tg) | ((((unsigned)((V) >> 32)) & 0xFFu) ^ tg))

#define STEP(BLK, CRE, CIM, NRE, NIM) do {                                           \
        const int blk = (BLK);                                                       \
        const int par = blk & 1;                                                     \
        const unsigned tg = (unsigned)(iter * 512 + blk + 1) & 0xFFu;                \
        __syncthreads();   /* x_l / LDS reuse boundary */                            \
        /* ---- Phase A: partial z[b,w] over own 128-d chunk (H from CUR bank), */   \
        /* stores carry the step tag in each float's low mantissa byte ---- */       \
        float2 xr0 = x_l[sub * 4 + 0], xr1 = x_l[sub * 4 + 1];                       \
        float2 xr2 = x_l[sub * 4 + 2], xr3 = x_l[sub * 4 + 3];                       \
        _Pragma("unroll")                                                            \
        for (int j = 0; j < 8; ++j) {                                                \
            float4 hr = CRE[j], hi = CIM[j];                                         \
            float sr, si;                                                            \
            sr  = xr0.x * hr.x - xr0.y * hi.x;  si  = xr0.x * hi.x + xr0.y * hr.x;   \
            sr += xr1.x * hr.y - xr1.y * hi.y;  si += xr1.x * hi.y + xr1.y * hr.y;   \
            sr += xr2.x * hr.z - xr2.y * hi.z;  si += xr2.x * hi.z + xr2.y * hr.z;   \
            sr += xr3.x * hr.w - xr3.y * hi.w;  si += xr3.x * hi.w + xr3.y * hr.w;   \
            _Pragma("unroll")                                                        \
            for (int m = 1; m < 32; m <<= 1) {                                       \
                sr += __shfl_xor(sr, m); si += __shfl_xor(si, m);                    \
            }                                                                        \
            if (sub == 0)                                                            \
                st_u64(&partuw[(size_t)par * 4096 + (b * 64 + rbase + 8 * j) * 8 + c], \
                       pack2(sr, si, tg));                                           \
        }                                                                            \
        /* ---- cheap LLC loads BEFORE the poll: tau(blk+1), y(blk) ---- */          \
        float tau_nxt = 0.0f;                                                        \
        if (t < 64) tau_nxt = ld_f(&tauws[(((blk + 1) & 511) * 8 + b) * 64 + t]);    \
        float yAr, yAi, yBr, yBi;                                                    \
        {                                                                            \
            int b1 = t >> 6, w1 = t & 63, n1 = blk * 64 + w1;                        \
            if (n1 < 16384) { yAr = y_re[b1 * 16384 + n1];         yAi = y_im[b1 * 16384 + n1]; } \
            else            { yAr = y_re[b1 * 16384 + n1 - 16384]; yAi = -y_im[b1 * 16384 + n1 - 16384]; } \
            int i2 = t + 256;                                                        \
            int b2 = i2 >> 6, w2 = i2 & 63, n2 = blk * 64 + w2;                      \
            if (n2 < 16384) { yBr = y_re[b2 * 16384 + n2];         yBi = y_im[b2 * 16384 + n2]; } \
            else            { yBr = y_re[b2 * 16384 + n2 - 16384]; yBi = -y_im[b2 * 16384 + n2 - 16384]; } \
        }                                                                            \
        /* ---- Phase B: MERGED poll of both row-slots ---- */                       \
        /* NOTE: H PREF is intentionally NOT issued yet — vmcnt retires in FIFO */   \
        /* order, so any load issued before the poll serializes into the first */    \
        /* poll round's waitcnt. ---- */                                             \
        float zr0, zi0, zr1, zi1;                                                    \
        {                                                                            \
            const ull* p0 = partuw + (size_t)par * 4096 + (size_t)t * 8;             \
            const ull* p1 = partuw + (size_t)par * 4096 + (size_t)(t + 256) * 8;     \
            ull v0,v1,v2,v3,v4,v5,v6,v7,u0,u1,u2,u3,u4,u5,u6,u7;                     \
            bool ok = false;                                                         \
            while (!ok) {                                                            \
                v0=ld_u64(p0+0); v1=ld_u64(p0+1); v2=ld_u64(p0+2); v3=ld_u64(p0+3);  \
                v4=ld_u64(p0+4); v5=ld_u64(p0+5); v6=ld_u64(p0+6); v7=ld_u64(p0+7);  \
                u0=ld_u64(p1+0); u1=ld_u64(p1+1); u2=ld_u64(p1+2); u3=ld_u64(p1+3);  \
                u4=ld_u64(p1+4); u5=ld_u64(p1+5); u6=ld_u64(p1+6); u7=ld_u64(p1+7);  \
                unsigned mm = TCHK(v0)|TCHK(v1)|TCHK(v2)|TCHK(v3)                    \
                            | TCHK(v4)|TCHK(v5)|TCHK(v6)|TCHK(v7)                    \
                            | TCHK(u0)|TCHK(u1)|TCHK(u2)|TCHK(u3)                    \
                            | TCHK(u4)|TCHK(u5)|TCHK(u6)|TCHK(u7);                   \
                ok = (mm == 0u);                                                     \
                if (!ok) __builtin_amdgcn_s_sleep(1);                                \
            }                                                                        \
            zr0 = __uint_as_float((unsigned)v0) + __uint_as_float((unsigned)v1)      \
                + __uint_as_float((unsigned)v2) + __uint_as_float((unsigned)v3)      \
                + __uint_as_float((unsigned)v4) + __uint_as_float((unsigned)v5)      \
                + __uint_as_float((unsigned)v6) + __uint_as_float((unsigned)v7);     \
            zi0 = __uint_as_float((unsigned)(v0>>32)) + __uint_as_float((unsigned)(v1>>32)) \
                + __uint_as_float((unsigned)(v2>>32)) + __uint_as_float((unsigned)(v3>>32)) \
                + __uint_as_float((unsigned)(v4>>32)) + __uint_as_float((unsigned)(v5>>32)) \
                + __uint_as_float((unsigned)(v6>>32)) + __uint_as_float((unsigned)(v7>>32));\
            zr1 = __uint_as_float((unsigned)u0) + __uint_as_float((unsigned)u1)      \
                + __uint_as_float((unsigned)u2) + __uint_as_float((unsigned)u3)      \
                + __uint_as_float((unsigned)u4) + __uint_as_float((unsigned)u5)      \
                + __uint_as_float((unsigned)u6) + __uint_as_float((unsigned)u7);     \
            zi1 = __uint_as_float((unsigned)(u0>>32)) + __uint_as_float((unsigned)(u1>>32)) \
                + __uint_as_float((unsigned)(u2>>32)) + __uint_as_float((unsigned)(u3>>32)) \
                + __uint_as_float((unsigned)(u4>>32)) + __uint_as_float((unsigned)(u5>>32)) \
                + __uint_as_float((unsigned)(u6>>32)) + __uint_as_float((unsigned)(u7>>32));\
        }                                                                            \
        /* ---- fence, then issue next H bank: overlaps stats+MLP+C+next-A ---- */   \
        __builtin_amdgcn_sched_barrier(0);                                           \
        PREF(NRE, NIM, ((blk + 1) & 511));                                           \
        __builtin_amdgcn_sched_barrier(0);                                           \
        {                                                                            \
            float rr0 = yAr - zr0, ri0 = yAi - zi0;                                  \
            float rr1 = yBr - zr1, ri1 = yBi - zi1;                                  \
            a2s[t] = rr0 * rr0 + ri0 * ri0;                                          \
            a2s[t + 256] = rr1 * rr1 + ri1 * ri1;                                    \
            if ((t >> 6) == b)         rown[t & 63] = make_float2(rr0, ri0);         \
            if (((t + 256) >> 6) == b) rown[t & 63] = make_float2(rr1, ri1);         \
        }                                                                            \
        __syncthreads();                                                             \
        /* ---- std(global, ddof=1), sigma2(b) ---- */                               \
        float va = a2s[t] + a2s[t + 256];                                            \
        float s_ = wsum64(va);                                                       \
        if (lane == 0) redl[wv] = s_;                                                \
        __syncthreads();                                                             \
        float mean = (redl[0] + redl[1] + redl[2] + redl[3]) * (1.0f / 512.0f);      \
        float d0 = a2s[t] - mean, d1 = a2s[t + 256] - mean;                          \
        float s2_ = wsum64(d0 * d0 + d1 * d1);                                       \
        float sg  = wsum64(a2s[b * 64 + lane]) * (1.0f / 64.0f);                     \
        if (lane == 0) redl[4 + wv] = s2_;                                           \
        __syncthreads();                                                             \
        float stdv = sqrtf((redl[4] + redl[5] + redl[6] + redl[7]) * (1.0f / 511.0f)); \
        if (t < 64) xts[t] = a2s[b * 64 + t] / stdv;                                 \
        __syncthreads();                                                             \
        /* ---- MLP layer 1: 256-thread 4-way k-split ---- */                        \
        {                                                                            \
            int j = t & 63, q = t >> 6;                                              \
            float acc = 0.0f;                                                        \
            _Pragma("unroll")                                                        \
            for (int k16 = 0; k16 < 16; ++k16) {                                     \
                int k = q * 16 + k16;                                                \
                acc += wTe[k * 64 + j] * xts[k];                                     \
            }                                                                        \
            mpartf[q * 64 + j] = acc;                                                \
        }                                                                            \
        __syncthreads();                                                             \
        if (t < 64) {                                                                \
            float acc = be[t] + mpartf[t] + mpartf[64 + t] + mpartf[128 + t] + mpartf[192 + t]; \
            hts[t] = 1.0f / (1.0f + expf(-acc));                                     \
        }                                                                            \
        __syncthreads();                                                             \
        /* ---- MLP layer 2: update + memory, 4-way k-split ---- */                  \
        {                                                                            \
            int j = t & 63, q = t >> 6;                                              \
            float acc = 0.0f;                                                        \
            _Pragma("unroll")                                                        \
            for (int k16 = 0; k16 < 16; ++k16) {                                     \
                int k = q * 16 + k16;                                                \
                acc += wTu[k * 64 + j] * hts[k] + wTm[k * 64 + j] * taurow[k];       \
            }                                                                        \
            mpartf[q * 64 + j] = acc;                                                \
        }                                                                            \
        __syncthreads();                                                             \
        if (t < 64) {                                                                \
            float tn = bu[t] + bm[t] + mpartf[t] + mpartf[64 + t] + mpartf[128 + t] + mpartf[192 + t]; \
            tn = fmaxf(tn, 0.0f);                                                    \
            if (c == 0) st_f(&tauws[(blk * 8 + b) * 64 + t], tn);                    \
            float2 rv = rown[t];                                                     \
            float scl = tn / sg;                                                     \
            resid[t] = make_float2(rv.x * scl, rv.y * scl);                          \
        }                                                                            \
        __syncthreads();                                                             \
        /* ---- Phase C: x[b, own chunk] += resid @ conj(H) / 65536 (CUR bank) */    \
        float2 ac0 = make_float2(0.f, 0.f), ac1 = make_float2(0.f, 0.f);             \
        float2 ac2 = make_float2(0.f, 0.f), ac3 = make_float2(0.f, 0.f);             \
        _Pragma("unroll")                                                            \
        for (int j = 0; j < 8; ++j) {                                                \
            float2 rs2 = resid[rbase + 8 * j];                                       \
            float4 hr = CRE[j], hi = CIM[j];                                         \
            ac0.x += rs2.x * hr.x + rs2.y * hi.x;  ac0.y += rs2.y * hr.x - rs2.x * hi.x; \
            ac1.x += rs2.x * hr.y + rs2.y * hi.y;  ac1.y += rs2.y * hr.y - rs2.x * hi.y; \
            ac2.x += rs2.x * hr.z + rs2.y * hi.z;  ac2.y += rs2.y * hr.z - rs2.x * hi.z; \
            ac3.x += rs2.x * hr.w + rs2.y * hi.w;  ac3.y += rs2.y * hr.w - rs2.x * hi.w; \
        }                                                                            \
        ac0.x += __shfl_xor(ac0.x, 32); ac0.y += __shfl_xor(ac0.y, 32);              \
        ac1.x += __shfl_xor(ac1.x, 32); ac1.y += __shfl_xor(ac1.y, 32);              \
        ac2.x += __shfl_xor(ac2.x, 32); ac2.y += __shfl_xor(ac2.y, 32);              \
        ac3.x += __shfl_xor(ac3.x, 32); ac3.y += __shfl_xor(ac3.y, 32);              \
        if ((t & 32) == 0) {                                                         \
            cpartC[wv][sub][0] = ac0; cpartC[wv][sub][1] = ac1;                      \
            cpartC[wv][sub][2] = ac2; cpartC[wv][sub][3] = ac3;                      \
        }                                                                            \
        if (t < 64) taurow[t] = tau_nxt;       /* commit prefetched tau */           \
        __syncthreads();                                                             \
        if (t < 128) {                                                               \
            int sl = t >> 2, kk = t & 3;                                             \
            float2 s0 = cpartC[0][sl][kk], s1 = cpartC[1][sl][kk];                   \
            float2 s2 = cpartC[2][sl][kk], s3 = cpartC[3][sl][kk];                   \
            float2 xv = x_l[t];                                                      \
            xv.x += (s0.x + s1.x + s2.x + s3.x) * (1.0f / 65536.0f);                 \
            xv.y += (s0.y + s1.y + s2.y + s3.y) * (1.0f / 65536.0f);                 \
            x_l[t] = xv;                                                             \
        }                                                                            \
    } while (0)

    #pragma unroll 1
    for (int iter = 0; iter < 10; ++iter) {
        #pragma unroll 1
        for (int blk2 = 0; blk2 < 512; blk2 += 2) {
            STEP(blk2,     hAre, hAim, hBre, hBim);
            STEP(blk2 + 1, hBre, hBim, hAre, hAim);
        }

        // ---- soft threshold: x = sgn(x) * relu(|x| - 1e-3 * max|x| (global)) ----
        const unsigned itg = (unsigned)(iter + 1);   // 1..10 (never 255/0xAA)
        float lm = 0.0f;
        if (t < 128) { float2 xv = x_l[t]; lm = sqrtf(xv.x * xv.x + xv.y * xv.y); }
        lm = wmax64(lm);
        if (lane == 0) redl[wv] = lm;
        __syncthreads();   // redl ready; also drains this WG's tau stores
        if (t == 0)
            st_u_rel(&pm_u[g], tagf(fmaxf(fmaxf(redl[0], redl[1]), fmaxf(redl[2], redl[3])), itg));
        float pv = 0.0f;
        if (t < 64) {
            unsigned u;
            for (;;) {
                u = ld_u(&pm_u[t]);
                if ((u & 0xFFu) == itg) break;
                __builtin_amdgcn_s_sleep(1);
            }
            pv = __uint_as_float(u);
        }
        __builtin_amdgcn_fence(__ATOMIC_ACQUIRE, "agent");
        pv = wmax64(pv);
        if (t == 0) gmax[0] = pv;
        __syncthreads();
        float m = gmax[0];
        if (t < 128) {
            float2 xv = x_l[t];
            float ax = sqrtf(xv.x * xv.x + xv.y * xv.y);
            float s = (ax > 0.0f) ? fmaxf(ax - 1e-3f * m, 0.0f) / ax : 0.0f;
            x_l[t] = make_float2(xv.x * s, xv.y * s);
        }
        __syncthreads();
    } // iter

    // ---------------- output ----------------
    // (final pm poll at iter 9 + acquire fence orders all WGs' tau writes
    //  before these reads)
    if (t < 128) out[b * 1024 + c * 128 + t] = x_l[t].x;
    for (int i = g * 8; i < g * 8 + 8; ++i) {
        for (int idx = t; idx < 512; idx += NT) {
            int bb = idx >> 6, w = idx & 63;
            out[8192 + bb * 32768 + i * 64 + w] = ld_f(&tauws[(i * 8 + bb) * 64 + w]);
        }
    }
#undef STEP
#undef TCHK
#undef PREF
}

// Diagnostic: if the launch is rejected, stamp the error code into output-0
// as code-distinguishable-through-bf16 multiples of 1e6.
__global__ void robii_diag_kernel(float* out, int code) {
    int i = blockIdx.x * blockDim.x + threadIdx.x;
    if (i < 8192) out[i] = 1.0e6f * (float)(1 + code);
}

extern "C" void kernel_launch(void* const* d_in, const int* in_sizes, int n_in,
                              void* d_out, int out_size, void* d_ws, size_t ws_size,
                              hipStream_t stream) {
    (void)in_sizes; (void)n_in; (void)out_size; (void)ws_size;
    const float* y_re     = (const float*)d_in[0];
    const float* y_im     = (const float*)d_in[1];
    const float* H_re     = (const float*)d_in[2];
    const float* H_im     = (const float*)d_in[3];
    const float* estep_w  = (const float*)d_in[4];
    const float* estep_b  = (const float*)d_in[5];
    const float* update_w = (const float*)d_in[6];
    const float* update_b = (const float*)d_in[7];
    const float* memory_w = (const float*)d_in[8];
    const float* memory_b = (const float*)d_in[9];
    float* outp = (float*)d_out;
    float* wsp  = (float*)d_ws;

    // plain (non-cooperative) launch — 64 blocks on 256 CUs always co-resident
    hipLaunchKernelGGL(robii_kernel, dim3(NWG), dim3(NT), 0, stream,
                       y_re, y_im, H_re, H_im, estep_w, estep_b,
                       update_w, update_b, memory_w, memory_b, outp, wsp);
    hipError_t e = hipGetLastError();
    if (e != hipSuccess) {
        hipLaunchKernelGGL(robii_diag_kernel, dim3(32), dim3(256), 0, stream,
                           outp, (int)e);
    }
}

// Round 18
// 37756.482 us; speedup vs baseline: 2.1841x; 1.0833x over previous
//
#include <hip/hip_runtime.h>
#include <math.h>

#define NT  256
#define NWG 64
#define SCOPE_AG __HIP_MEMORY_SCOPE_AGENT
typedef unsigned long long ull;

// ---------- agent-scope (coherence-point) atomic helpers ----------
__device__ __forceinline__ float ld_f(const float* p) {
    return __hip_atomic_load(p, __ATOMIC_RELAXED, SCOPE_AG);
}
__device__ __forceinline__ void st_f(float* p, float v) {
    __hip_atomic_store(p, v, __ATOMIC_RELAXED, SCOPE_AG);
}
__device__ __forceinline__ unsigned ld_u(const unsigned* p) {
    return __hip_atomic_load(p, __ATOMIC_RELAXED, SCOPE_AG);
}
__device__ __forceinline__ void st_u(unsigned* p, unsigned v) {
    __hip_atomic_store(p, v, __ATOMIC_RELAXED, SCOPE_AG);
}
__device__ __forceinline__ void st_u_rel(unsigned* p, unsigned v) {
    __hip_atomic_store(p, v, __ATOMIC_RELEASE, SCOPE_AG);
}
__device__ __forceinline__ ull ld_u64(const ull* p) {
    return __hip_atomic_load(p, __ATOMIC_RELAXED, SCOPE_AG);
}
__device__ __forceinline__ void st_u64(ull* p, ull v) {
    __hip_atomic_store(p, v, __ATOMIC_RELAXED, SCOPE_AG);
}

// mantissa tag: low 8 bits of the float carry the epoch tag (noise ~2^-17 rel)
__device__ __forceinline__ unsigned tagf(float v, unsigned tg) {
    return (__float_as_uint(v) & 0xFFFFFF00u) | tg;
}
__device__ __forceinline__ ull pack2(float lo, float hi, unsigned tg) {
    return ((ull)tagf(hi, tg) << 32) | (ull)tagf(lo, tg);
}

__device__ __forceinline__ float wsum64(float v) {
    #pragma unroll
    for (int m = 1; m < 64; m <<= 1) v += __shfl_xor(v, m);
    return v;
}
__device__ __forceinline__ float wmax64(float v) {
    #pragma unroll
    for (int m = 1; m < 64; m <<= 1) v = fmaxf(v, __shfl_xor(v, m));
    return v;
}

// ws layout (floats) — total 278,592 floats = 1,114,368 B (proven-safe):
//   partuw: ull[2 par][512 (b,w)][8 c]   @ 0       (16384 floats)
//           each u64 = two mantissa-tagged floats (re lo, im hi)
//           tag = (iter*512+blk+1) & 0xFF
//   tauws:  float[512 blk][8 b][64 w]    @ 16384   (262144 floats)
//   pm_u:   unsigned[64]                 @ 278528  (tagged floats; tag=iter+1, init=255)
//
// Protocol: consumers poll partial words until BOTH halves carry the step tag.
// 2-parity bounded-lead => a buffer always holds tag s or s-2 (never ==s early);
// cross-replay stale tags 127/128 vs first polls 1/2; 0xAA poison != 1/2.

__launch_bounds__(NT, 1)
__global__ void robii_kernel(
    const float* __restrict__ y_re, const float* __restrict__ y_im,
    const float* __restrict__ H_re, const float* __restrict__ H_im,
    const float* __restrict__ estep_w, const float* __restrict__ estep_b,
    const float* __restrict__ update_w, const float* __restrict__ update_b,
    const float* __restrict__ memory_w, const float* __restrict__ memory_b,
    float* __restrict__ out, float* __restrict__ ws)
{
    __shared__ float wTe[4096], wTu[4096], wTm[4096];  // transposed: wT[k*64+j] = w[j][k]
    __shared__ float be[64], bu[64], bm[64];
    __shared__ float a2s[512];
    __shared__ float redl[8];
    __shared__ float gmax[1];
    __shared__ float2 rown[64];
    __shared__ float xts[64], hts[64], taurow[64];
    __shared__ float2 resid[64];
    __shared__ float2 cpartC[4][32][4];   // Phase-C scratch; aliased as MLP partials
    __shared__ float2 x_l[128];     // this WG's x[b, c*128 .. c*128+127]

    float* mpartf = (float*)cpartC;  // [4][64] floats (time-shared with Phase C)

    const int g = blockIdx.x, t = threadIdx.x;
    const int c = g & 7;        // d-chunk owned
    const int b = g >> 3;       // batch owned
    const int lane = t & 63, wv = t >> 6;
    const int sub = t & 31;     // column slice (4 floats)
    const int rbase = t >> 5;   // row group 0..7 (rows rbase+8j)

    ull*      partuw = (ull*)ws;                 // [2][512][8] u64
    float*    tauws  = ws + 16384;               // [512][8][64]
    unsigned* pm_u   = (unsigned*)(ws + 278528); // [64] tagged floats

    // ---------------- init ----------------
    for (int i = t; i < 4096; i += NT) {
        int j = i >> 6, k = i & 63;
        wTe[k * 64 + j] = estep_w[i];
        wTu[k * 64 + j] = update_w[i];
        wTm[k * 64 + j] = memory_w[i];
    }
    if (t < 64) { be[t] = estep_b[t]; bu[t] = update_b[t]; bm[t] = memory_b[t]; taurow[t] = 1.0f; }
    if (t < 128) x_l[t] = make_float2(0.0f, 0.0f);
    for (int i = t; i < 4096; i += NT) st_f(&tauws[g * 4096 + i], 1.0f);

    // init sync via tagged pm (tag 255): publishes tau init.
    __syncthreads();                              // drains this WG's tau stores
    if (t == 0) st_u_rel(&pm_u[g], tagf(1.0f, 255u));
    if (t < 64) {
        while ((ld_u(&pm_u[t]) & 0xFFu) != 255u) __builtin_amdgcn_s_sleep(1);
    }
    __builtin_amdgcn_fence(__ATOMIC_ACQUIRE, "agent");
    __syncthreads();

    const size_t hcol = (size_t)c * 128 + (size_t)sub * 4;

    // H double-buffer register banks
    float4 hAre[8], hAim[8], hBre[8], hBim[8];

#define PREF(DRE, DIM_, BLKN) do {                                                   \
        const float* _pr = H_re + ((size_t)(BLKN) * 64 + rbase) * 1024 + hcol;       \
        const float* _pi = H_im + ((size_t)(BLKN) * 64 + rbase) * 1024 + hcol;       \
        _Pragma("unroll")                                                            \
        for (int _j = 0; _j < 8; ++_j) {                                             \
            DRE[_j]  = *(const float4*)(_pr + (size_t)_j * 8192);                    \
            DIM_[_j] = *(const float4*)(_pi + (size_t)_j * 8192);                    \
        }                                                                            \
    } while (0)

    PREF(hAre, hAim, 0);   // prologue: bank A <- block 0

#define STEP(BLK, CRE, CIM, NRE, NIM) do {                                           \
        const int blk = (BLK);                                                       \
        const int par = blk & 1;                                                     \
        const unsigned tg = (unsigned)(iter * 512 + blk + 1) & 0xFFu;                \
        __syncthreads();   /* x_l / LDS reuse boundary */                            \
        /* ---- Phase A: partial z[b,w] over own 128-d chunk (H from CUR bank), */   \
        /* stores carry the step tag in each float's low mantissa byte ---- */       \
        float2 xr0 = x_l[sub * 4 + 0], xr1 = x_l[sub * 4 + 1];                       \
        float2 xr2 = x_l[sub * 4 + 2], xr3 = x_l[sub * 4 + 3];                       \
        _Pragma("unroll")                                                            \
        for (int j = 0; j < 8; ++j) {                                                \
            float4 hr = CRE[j], hi = CIM[j];                                         \
            float sr, si;                                                            \
            sr  = xr0.x * hr.x - xr0.y * hi.x;  si  = xr0.x * hi.x + xr0.y * hr.x;   \
            sr += xr1.x * hr.y - xr1.y * hi.y;  si += xr1.x * hi.y + xr1.y * hr.y;   \
            sr += xr2.x * hr.z - xr2.y * hi.z;  si += xr2.x * hi.z + xr2.y * hr.z;   \
            sr += xr3.x * hr.w - xr3.y * hi.w;  si += xr3.x * hi.w + xr3.y * hr.w;   \
            _Pragma("unroll")                                                        \
            for (int m = 1; m < 32; m <<= 1) {                                       \
                sr += __shfl_xor(sr, m); si += __shfl_xor(si, m);                    \
            }                                                                        \
            if (sub == 0)                                                            \
                st_u64(&partuw[(size_t)par * 4096 + (b * 64 + rbase + 8 * j) * 8 + c], \
                       pack2(sr, si, tg));                                           \
        }                                                                            \
        /* ---- overlap: prefetch H(blk+1) + tau(blk+1) + y(blk) ---- */             \
        PREF(NRE, NIM, ((blk + 1) & 511));                                           \
        float tau_nxt = 0.0f;                                                        \
        if (t < 64) tau_nxt = ld_f(&tauws[(((blk + 1) & 511) * 8 + b) * 64 + t]);    \
        float yAr, yAi, yBr, yBi;                                                    \
        {                                                                            \
            int b1 = t >> 6, w1 = t & 63, n1 = blk * 64 + w1;                        \
            if (n1 < 16384) { yAr = y_re[b1 * 16384 + n1];         yAi = y_im[b1 * 16384 + n1]; } \
            else            { yAr = y_re[b1 * 16384 + n1 - 16384]; yAi = -y_im[b1 * 16384 + n1 - 16384]; } \
            int i2 = t + 256;                                                        \
            int b2 = i2 >> 6, w2 = i2 & 63, n2 = blk * 64 + w2;                      \
            if (n2 < 16384) { yBr = y_re[b2 * 16384 + n2];         yBi = y_im[b2 * 16384 + n2]; } \
            else            { yBr = y_re[b2 * 16384 + n2 - 16384]; yBi = -y_im[b2 * 16384 + n2 - 16384]; } \
        }                                                                            \
        /* ---- Phase B: poll tagged partials (flag==data, zero extra bytes) ---- */ \
        _Pragma("unroll")                                                            \
        for (int e = 0; e < 2; ++e) {                                                \
            int idx = t + e * 256;                                                   \
            const ull* pb = partuw + (size_t)par * 4096 + (size_t)idx * 8;           \
            ull v0, v1, v2, v3, v4, v5, v6, v7;                                      \
            bool ok = false;                                                         \
            while (!ok) {                                                            \
                v0 = ld_u64(pb + 0); v1 = ld_u64(pb + 1);                            \
                v2 = ld_u64(pb + 2); v3 = ld_u64(pb + 3);                            \
                v4 = ld_u64(pb + 4); v5 = ld_u64(pb + 5);                            \
                v6 = ld_u64(pb + 6); v7 = ld_u64(pb + 7);                            \
                unsigned m01 = ((unsigned)v0 & 0xFFu) ^ tg;                          \
                m01 |= ((unsigned)(v0 >> 32) & 0xFFu) ^ tg;                          \
                m01 |= ((unsigned)v1 & 0xFFu) ^ tg;                                  \
                m01 |= ((unsigned)(v1 >> 32) & 0xFFu) ^ tg;                          \
                m01 |= ((unsigned)v2 & 0xFFu) ^ tg;                                  \
                m01 |= ((unsigned)(v2 >> 32) & 0xFFu) ^ tg;                          \
                m01 |= ((unsigned)v3 & 0xFFu) ^ tg;                                  \
                m01 |= ((unsigned)(v3 >> 32) & 0xFFu) ^ tg;                          \
                m01 |= ((unsigned)v4 & 0xFFu) ^ tg;                                  \
                m01 |= ((unsigned)(v4 >> 32) & 0xFFu) ^ tg;                          \
                m01 |= ((unsigned)v5 & 0xFFu) ^ tg;                                  \
                m01 |= ((unsigned)(v5 >> 32) & 0xFFu) ^ tg;                          \
                m01 |= ((unsigned)v6 & 0xFFu) ^ tg;                                  \
                m01 |= ((unsigned)(v6 >> 32) & 0xFFu) ^ tg;                          \
                m01 |= ((unsigned)v7 & 0xFFu) ^ tg;                                  \
                m01 |= ((unsigned)(v7 >> 32) & 0xFFu) ^ tg;                          \
                ok = (m01 == 0u);                                                    \
                if (!ok) __builtin_amdgcn_s_sleep(1);                                \
            }                                                                        \
            float zr = __uint_as_float((unsigned)v0) + __uint_as_float((unsigned)v1) \
                     + __uint_as_float((unsigned)v2) + __uint_as_float((unsigned)v3) \
                     + __uint_as_float((unsigned)v4) + __uint_as_float((unsigned)v5) \
                     + __uint_as_float((unsigned)v6) + __uint_as_float((unsigned)v7);\
            float zi = __uint_as_float((unsigned)(v0 >> 32)) + __uint_as_float((unsigned)(v1 >> 32)) \
                     + __uint_as_float((unsigned)(v2 >> 32)) + __uint_as_float((unsigned)(v3 >> 32)) \
                     + __uint_as_float((unsigned)(v4 >> 32)) + __uint_as_float((unsigned)(v5 >> 32)) \
                     + __uint_as_float((unsigned)(v6 >> 32)) + __uint_as_float((unsigned)(v7 >> 32));\
            float rr = ((e == 0) ? yAr : yBr) - zr;                                  \
            float ri = ((e == 0) ? yAi : yBi) - zi;                                  \
            a2s[idx] = rr * rr + ri * ri;                                            \
            int b1 = idx >> 6, w = idx & 63;                                         \
            if (b1 == b) rown[w] = make_float2(rr, ri);                              \
        }                                                                            \
        __syncthreads();                                                             \
        /* ---- std(global, ddof=1), sigma2(b) ---- */                               \
        float va = a2s[t] + a2s[t + 256];                                            \
        float s_ = wsum64(va);                                                       \
        if (lane == 0) redl[wv] = s_;                                                \
        __syncthreads();                                                             \
        float mean = (redl[0] + redl[1] + redl[2] + redl[3]) * (1.0f / 512.0f);      \
        float d0 = a2s[t] - mean, d1 = a2s[t + 256] - mean;                          \
        float s2_ = wsum64(d0 * d0 + d1 * d1);                                       \
        float sg  = wsum64(a2s[b * 64 + lane]) * (1.0f / 64.0f);                     \
        if (lane == 0) redl[4 + wv] = s2_;                                           \
        __syncthreads();                                                             \
        float stdv = sqrtf((redl[4] + redl[5] + redl[6] + redl[7]) * (1.0f / 511.0f)); \
        if (t < 64) xts[t] = a2s[b * 64 + t] / stdv;                                 \
        __syncthreads();                                                             \
        /* ---- MLP layer 1: 256-thread 4-way k-split ---- */                        \
        {                                                                            \
            int j = t & 63, q = t >> 6;                                              \
            float acc = 0.0f;                                                        \
            _Pragma("unroll")                                                        \
            for (int k16 = 0; k16 < 16; ++k16) {                                     \
                int k = q * 16 + k16;                                                \
                acc += wTe[k * 64 + j] * xts[k];                                     \
            }                                                                        \
            mpartf[q * 64 + j] = acc;                                                \
        }                                                                            \
        __syncthreads();                                                             \
        if (t < 64) {                                                                \
            float acc = be[t] + mpartf[t] + mpartf[64 + t] + mpartf[128 + t] + mpartf[192 + t]; \
            hts[t] = 1.0f / (1.0f + expf(-acc));                                     \
        }                                                                            \
        __syncthreads();                                                             \
        /* ---- MLP layer 2: update + memory, 4-way k-split ---- */                  \
        {                                                                            \
            int j = t & 63, q = t >> 6;                                              \
            float acc = 0.0f;                                                        \
            _Pragma("unroll")                                                        \
            for (int k16 = 0; k16 < 16; ++k16) {                                     \
                int k = q * 16 + k16;                                                \
                acc += wTu[k * 64 + j] * hts[k] + wTm[k * 64 + j] * taurow[k];       \
            }                                                                        \
            mpartf[q * 64 + j] = acc;                                                \
        }                                                                            \
        __syncthreads();                                                             \
        if (t < 64) {                                                                \
            float tn = bu[t] + bm[t] + mpartf[t] + mpartf[64 + t] + mpartf[128 + t] + mpartf[192 + t]; \
            tn = fmaxf(tn, 0.0f);                                                    \
            if (c == 0) st_f(&tauws[(blk * 8 + b) * 64 + t], tn);                    \
            float2 rv = rown[t];                                                     \
            float scl = tn / sg;                                                     \
            resid[t] = make_float2(rv.x * scl, rv.y * scl);                          \
        }                                                                            \
        __syncthreads();                                                             \
        /* ---- Phase C: x[b, own chunk] += resid @ conj(H) / 65536 (CUR bank) */    \
        float2 ac0 = make_float2(0.f, 0.f), ac1 = make_float2(0.f, 0.f);             \
        float2 ac2 = make_float2(0.f, 0.f), ac3 = make_float2(0.f, 0.f);             \
        _Pragma("unroll")                                                            \
        for (int j = 0; j < 8; ++j) {                                                \
            float2 rs2 = resid[rbase + 8 * j];                                       \
            float4 hr = CRE[j], hi = CIM[j];                                         \
            ac0.x += rs2.x * hr.x + rs2.y * hi.x;  ac0.y += rs2.y * hr.x - rs2.x * hi.x; \
            ac1.x += rs2.x * hr.y + rs2.y * hi.y;  ac1.y += rs2.y * hr.y - rs2.x * hi.y; \
            ac2.x += rs2.x * hr.z + rs2.y * hi.z;  ac2.y += rs2.y * hr.z - rs2.x * hi.z; \
            ac3.x += rs2.x * hr.w + rs2.y * hi.w;  ac3.y += rs2.y * hr.w - rs2.x * hi.w; \
        }                                                                            \
        ac0.x += __shfl_xor(ac0.x, 32); ac0.y += __shfl_xor(ac0.y, 32);              \
        ac1.x += __shfl_xor(ac1.x, 32); ac1.y += __shfl_xor(ac1.y, 32);              \
        ac2.x += __shfl_xor(ac2.x, 32); ac2.y += __shfl_xor(ac2.y, 32);              \
        ac3.x += __shfl_xor(ac3.x, 32); ac3.y += __shfl_xor(ac3.y, 32);              \
        if ((t & 32) == 0) {                                                         \
            cpartC[wv][sub][0] = ac0; cpartC[wv][sub][1] = ac1;                      \
            cpartC[wv][sub][2] = ac2; cpartC[wv][sub][3] = ac3;                      \
        }                                                                            \
        if (t < 64) taurow[t] = tau_nxt;       /* commit prefetched tau */           \
        __syncthreads();                                                             \
        if (t < 128) {                                                               \
            int sl = t >> 2, kk = t & 3;                                             \
            float2 s0 = cpartC[0][sl][kk], s1 = cpartC[1][sl][kk];                   \
            float2 s2 = cpartC[2][sl][kk], s3 = cpartC[3][sl][kk];                   \
            float2 xv = x_l[t];                                                      \
            xv.x += (s0.x + s1.x + s2.x + s3.x) * (1.0f / 65536.0f);                 \
            xv.y += (s0.y + s1.y + s2.y + s3.y) * (1.0f / 65536.0f);                 \
            x_l[t] = xv;                                                             \
        }                                                                            \
    } while (0)

    #pragma unroll 1
    for (int iter = 0; iter < 10; ++iter) {
        #pragma unroll 1
        for (int blk2 = 0; blk2 < 512; blk2 += 2) {
            STEP(blk2,     hAre, hAim, hBre, hBim);
            STEP(blk2 + 1, hBre, hBim, hAre, hAim);
        }

        // ---- soft threshold: x = sgn(x) * relu(|x| - 1e-3 * max|x| (global)) ----
        const unsigned itg = (unsigned)(iter + 1);   // 1..10 (never 255/0xAA)
        float lm = 0.0f;
        if (t < 128) { float2 xv = x_l[t]; lm = sqrtf(xv.x * xv.x + xv.y * xv.y); }
        lm = wmax64(lm);
        if (lane == 0) redl[wv] = lm;
        __syncthreads();   // redl ready; also drains this WG's tau stores
        if (t == 0)
            st_u_rel(&pm_u[g], tagf(fmaxf(fmaxf(redl[0], redl[1]), fmaxf(redl[2], redl[3])), itg));
        float pv = 0.0f;
        if (t < 64) {
            unsigned u;
            for (;;) {
                u = ld_u(&pm_u[t]);
                if ((u & 0xFFu) == itg) break;
                __builtin_amdgcn_s_sleep(1);
            }
            pv = __uint_as_float(u);
        }
        __builtin_amdgcn_fence(__ATOMIC_ACQUIRE, "agent");
        pv = wmax64(pv);
        if (t == 0) gmax[0] = pv;
        __syncthreads();
        float m = gmax[0];
        if (t < 128) {
            float2 xv = x_l[t];
            float ax = sqrtf(xv.x * xv.x + xv.y * xv.y);
            float s = (ax > 0.0f) ? fmaxf(ax - 1e-3f * m, 0.0f) / ax : 0.0f;
            x_l[t] = make_float2(xv.x * s, xv.y * s);
        }
        __syncthreads();
    } // iter

    // ---------------- output ----------------
    // (final pm poll at iter 9 + acquire fence orders all WGs' tau writes
    //  before these reads)
    if (t < 128) out[b * 1024 + c * 128 + t] = x_l[t].x;
    for (int i = g * 8; i < g * 8 + 8; ++i) {
        for (int idx = t; idx < 512; idx += NT) {
            int bb = idx >> 6, w = idx & 63;
            out[8192 + bb * 32768 + i * 64 + w] = ld_f(&tauws[(i * 8 + bb) * 64 + w]);
        }
    }
#undef STEP
#undef PREF
}

// Diagnostic: if the launch is rejected, stamp the error code into output-0
// as code-distinguishable-through-bf16 multiples of 1e6.
__global__ void robii_diag_kernel(float* out, int code) {
    int i = blockIdx.x * blockDim.x + threadIdx.x;
    if (i < 8192) out[i] = 1.0e6f * (float)(1 + code);
}

extern "C" void kernel_launch(void* const* d_in, const int* in_sizes, int n_in,
                              void* d_out, int out_size, void* d_ws, size_t ws_size,
                              hipStream_t stream) {
    (void)in_sizes; (void)n_in; (void)out_size; (void)ws_size;
    const float* y_re     = (const float*)d_in[0];
    const float* y_im     = (const float*)d_in[1];
    const float* H_re     = (const float*)d_in[2];
    const float* H_im     = (const float*)d_in[3];
    const float* estep_w  = (const float*)d_in[4];
    const float* estep_b  = (const float*)d_in[5];
    const float* update_w = (const float*)d_in[6];
    const float* update_b = (const float*)d_in[7];
    const float* memory_w = (const float*)d_in[8];
    const float* memory_b = (const float*)d_in[9];
    float* outp = (float*)d_out;
    float* wsp  = (float*)d_ws;

    // plain (non-cooperative) launch — 64 blocks on 256 CUs always co-resident
    hipLaunchKernelGGL(robii_kernel, dim3(NWG), dim3(NT), 0, stream,
                       y_re, y_im, H_re, H_im, estep_w, estep_b,
                       update_w, update_b, memory_w, memory_b, outp, wsp);
    hipError_t e = hipGetLastError();
    if (e != hipSuccess) {
        hipLaunchKernelGGL(robii_diag_kernel, dim3(32), dim3(256), 0, stream,
                           outp, (int)e);
    }
}